// Round 10
// baseline (357.725 us; speedup 1.0000x reference)
//
#include <hip/hip_runtime.h>
#include <math.h>

#define NB 16

// ---------------- shapes ----------------
// x:      (16, 3,16,128,128)
// y1:     (16, 4, 8, 64, 64)   conv1 k4 s2 p1 + relu
// y2:     (16, 8, 4, 32, 32)   conv2 k4 s2 p1 + relu
// z:      (16,16, 4, 32, 32)   conv4 k3 s1 p1 + clip(0,6)
// quant:  (16,16, 4, 32, 32)   VQ
// d1:     (16, 8, 8, 64, 64)   deconv1 k4 s2 p1 + relu  (padded: [10][66][72])
// d2:     (16, 4,16,128,128)   deconv3 k4 s2 p1 + relu  (padded: [18][130][136])
// out:    (16, 3,16,128,128)   deconv4 k3 s1 p1

// padded d2 geometry
#define P_STRIDE 136              // col = iw + 4; 16B-aligned rows
#define P_PLANE  (130 * P_STRIDE) // row = ih + 1
#define P_VOL    (18 * P_PLANE)   // plane = id + 1
// padded d1 geometry
#define D1_STRIDE 72              // col = iw + 4
#define D1_PLANE  (66 * D1_STRIDE)
#define D1_VOL    (10 * D1_PLANE)

__device__ __forceinline__ float4 ld4(const float* p) {
  return *reinterpret_cast<const float4*>(p);
}
__device__ __forceinline__ void st4(float* p, float4 v) {
  *reinterpret_cast<float4*>(p) = v;
}

// conv1 (R4 strip, measured fast): thread = 4 co x (1 od, 1 oh, 4 ow). 512 blocks.
__global__ __launch_bounds__(256) void conv1_k(
    const float* __restrict__ x, const float* __restrict__ w,
    const float* __restrict__ bias, float* __restrict__ y) {
  int idx = blockIdx.x * 256 + threadIdx.x;
  int g  = idx & 15;
  int oh = (idx >> 4) & 63;
  int od = (idx >> 10) & 7;
  int n  = idx >> 13;
  bool gl = (g > 0), gr = (g < 15);
  float acc[4][4];
  #pragma unroll
  for (int co = 0; co < 4; co++) {
    float bv = bias[co];
    #pragma unroll
    for (int m = 0; m < 4; m++) acc[co][m] = bv;
  }
  int ih0 = 2 * oh - 1;
  #pragma unroll 1
  for (int ci = 0; ci < 3; ci++) {
    #pragma unroll 1
    for (int kd = 0; kd < 4; kd++) {
      int id = 2 * od - 1 + kd;
      bool vd = (unsigned)id < 16u;
      int idc = vd ? id : 0;
      const float* plane = x + (((n * 3 + ci) * 16 + idc) * 16384);
      #pragma unroll
      for (int kh = 0; kh < 4; kh++) {
        int ih = ih0 + kh;
        bool v = vd && ((unsigned)ih < 128u);
        int ihc = (unsigned)ih < 128u ? ih : 0;
        const float* rp = plane + ihc * 128 + 8 * g;
        float r[10];
        float4 A = ld4(rp);
        float4 B = ld4(rp + 4);
        float rl = rp[-1 * (int)gl];
        float rr = rp[gr ? 8 : 0];
        r[0] = (v && gl) ? rl : 0.0f;
        r[1] = v ? A.x : 0.0f; r[2] = v ? A.y : 0.0f;
        r[3] = v ? A.z : 0.0f; r[4] = v ? A.w : 0.0f;
        r[5] = v ? B.x : 0.0f; r[6] = v ? B.y : 0.0f;
        r[7] = v ? B.z : 0.0f; r[8] = v ? B.w : 0.0f;
        r[9] = (v && gr) ? rr : 0.0f;
        #pragma unroll
        for (int co = 0; co < 4; co++) {
          const float* wb = w + ((co * 3 + ci) * 4 + kd) * 16 + kh * 4;
          #pragma unroll
          for (int kw = 0; kw < 4; kw++) {
            float wv = wb[kw];
            #pragma unroll
            for (int m = 0; m < 4; m++)
              acc[co][m] += r[2 * m + kw] * wv;
          }
        }
      }
    }
  }
  #pragma unroll
  for (int co = 0; co < 4; co++) {
    float4 o;
    o.x = fmaxf(acc[co][0], 0.0f); o.y = fmaxf(acc[co][1], 0.0f);
    o.z = fmaxf(acc[co][2], 0.0f); o.w = fmaxf(acc[co][3], 0.0f);
    st4(y + ((n * 4 + co) * 8 + od) * 4096 + oh * 64 + 4 * g, o);
  }
}

// conv2: thread = 1 pos x 4 co. 512 blocks.
__global__ __launch_bounds__(256) void conv2_k(
    const float* __restrict__ y1, const float* __restrict__ w,
    const float* __restrict__ bias, float* __restrict__ y) {
  int idx = blockIdx.x * 256 + threadIdx.x;
  int ow = idx & 31;
  int oh = (idx >> 5) & 31;
  int od = (idx >> 10) & 3;
  int n = (idx >> 12) & 15;
  int cog = idx >> 16;
  float acc[4];
  #pragma unroll
  for (int co = 0; co < 4; co++) acc[co] = bias[cog * 4 + co];
  int id0 = 2 * od - 1, ih0 = 2 * oh - 1, iw0 = 2 * ow - 1;
  bool vh[4], vw[4];
  #pragma unroll
  for (int l = 0; l < 4; l++) {
    vh[l] = (unsigned)(ih0 + l) < 64u;
    vw[l] = (unsigned)(iw0 + l) < 64u;
  }
  #pragma unroll 1
  for (int ci = 0; ci < 4; ci++) {
    const float* ip = y1 + ((n * 4 + ci) * 8) * 4096;
    #pragma unroll
    for (int kd = 0; kd < 4; kd++) {
      int id = id0 + kd;
      bool vd = (unsigned)id < 8u;
      const float* pp = ip + id * 4096;
      float p[4][4];
      #pragma unroll
      for (int kh = 0; kh < 4; kh++)
        #pragma unroll
        for (int kw = 0; kw < 4; kw++)
          p[kh][kw] = (vd && vh[kh] && vw[kw]) ? pp[(ih0 + kh) * 64 + (iw0 + kw)] : 0.0f;
      #pragma unroll
      for (int co = 0; co < 4; co++) {
        const float* wp = w + (((cog * 4 + co) * 4 + ci) * 4 + kd) * 16;
        #pragma unroll
        for (int kh = 0; kh < 4; kh++)
          #pragma unroll
          for (int kw = 0; kw < 4; kw++)
            acc[co] += p[kh][kw] * wp[kh * 4 + kw];
      }
    }
  }
  #pragma unroll
  for (int co = 0; co < 4; co++)
    y[((n * 8 + cog * 4 + co) * 4 + od) * 1024 + oh * 32 + ow] = fmaxf(acc[co], 0.0f);
}

// conv4: thread = 1 pos x 4 co. 1024 blocks.
__global__ __launch_bounds__(256) void conv4_k(
    const float* __restrict__ y2, const float* __restrict__ w,
    const float* __restrict__ bias, float* __restrict__ z) {
  int idx = blockIdx.x * 256 + threadIdx.x;
  int ow = idx & 31;
  int oh = (idx >> 5) & 31;
  int od = (idx >> 10) & 3;
  int n = (idx >> 12) & 15;
  int cog = idx >> 16;
  float acc[4];
  #pragma unroll
  for (int co = 0; co < 4; co++) acc[co] = bias[cog * 4 + co];
  bool vh[3], vw[3];
  #pragma unroll
  for (int l = 0; l < 3; l++) {
    vh[l] = (unsigned)(oh - 1 + l) < 32u;
    vw[l] = (unsigned)(ow - 1 + l) < 32u;
  }
  #pragma unroll 1
  for (int ci = 0; ci < 8; ci++) {
    const float* ip = y2 + ((n * 8 + ci) * 4) * 1024;
    #pragma unroll
    for (int kd = 0; kd < 3; kd++) {
      int id = od - 1 + kd;
      bool vd = (unsigned)id < 4u;
      const float* pp = ip + id * 1024;
      float p[3][3];
      #pragma unroll
      for (int kh = 0; kh < 3; kh++)
        #pragma unroll
        for (int kw = 0; kw < 3; kw++)
          p[kh][kw] = (vd && vh[kh] && vw[kw]) ? pp[(oh - 1 + kh) * 32 + (ow - 1 + kw)] : 0.0f;
      #pragma unroll
      for (int co = 0; co < 4; co++) {
        const float* wp = w + (((cog * 4 + co) * 8 + ci) * 3 + kd) * 9;
        #pragma unroll
        for (int kh = 0; kh < 3; kh++)
          #pragma unroll
          for (int kw = 0; kw < 3; kw++)
            acc[co] += p[kh][kw] * wp[kh * 3 + kw];
      }
    }
  }
  #pragma unroll
  for (int co = 0; co < 4; co++)
    z[((n * 16 + cog * 4 + co) * 4 + od) * 1024 + oh * 32 + ow] =
        fminf(fmaxf(acc[co], 0.0f), 6.0f);
}

// VQ (verified)
__global__ __launch_bounds__(256) void vq_k(
    const float* __restrict__ z, const float* __restrict__ emb,
    float* __restrict__ quant, float* __restrict__ codes_out,
    float* __restrict__ stats) {
  __shared__ float se[32 * 16];
  __shared__ float se2[32];
  __shared__ float shist[32];
  __shared__ float swred[4];
  int tid = threadIdx.x;
  for (int i = tid; i < 512; i += 256) {
    int r = i >> 4;
    float v = emb[i];
    if (r == 0) v = 0.0f;
    else if (r == 1) v = 6.0f;
    se[i] = v;
  }
  if (tid < 32) shist[tid] = 0.0f;
  __syncthreads();
  if (tid < 32) {
    float s = 0.0f;
    #pragma unroll
    for (int d = 0; d < 16; d++) { float v = se[tid * 16 + d]; s += v * v; }
    se2[tid] = s;
  }
  __syncthreads();

  int idx = blockIdx.x * 256 + tid;
  float lsum = 0.0f;
  {
    int w_ = idx & 31; int t = idx >> 5;
    int h_ = t & 31; t >>= 5;
    int d_ = t & 3;  int b_ = t >> 2;
    const float* zp = z + b_ * 65536 + d_ * 1024 + h_ * 32 + w_;
    float f[16];
    float f2 = 0.0f;
    #pragma unroll
    for (int c = 0; c < 16; c++) { float v = zp[c * 4096]; f[c] = v; f2 += v * v; }
    float best = 1e30f; int bi = 0;
    for (int e = 0; e < 32; e++) {
      float dot = 0.0f;
      #pragma unroll
      for (int c = 0; c < 16; c++) dot += f[c] * se[e * 16 + c];
      float d2 = f2 - 2.0f * dot + se2[e];
      if (d2 < best) { best = d2; bi = e; }
    }
    float* qp = quant + b_ * 65536 + d_ * 1024 + h_ * 32 + w_;
    #pragma unroll
    for (int c = 0; c < 16; c++) {
      float q = se[bi * 16 + c];
      qp[c * 4096] = q;
      float df = q - f[c];
      lsum += df * df;
    }
    codes_out[idx] = (float)bi;
    atomicAdd(&shist[bi], 1.0f);
  }
  for (int o = 32; o; o >>= 1) lsum += __shfl_down(lsum, o);
  if ((tid & 63) == 0) swred[tid >> 6] = lsum;
  __syncthreads();
  if (tid == 0) atomicAdd(&stats[0], swred[0] + swred[1] + swred[2] + swred[3]);
  if (tid < 32) {
    float h = shist[tid];
    if (h != 0.0f) atomicAdd(&stats[1 + tid], h);
  }
}

__global__ void init_stats_k(float* __restrict__ stats) {
  int tid = threadIdx.x;
  if (tid < 33) stats[tid] = 0.0f;
}

__global__ void fin_k(const float* __restrict__ stats,
                      const float* __restrict__ cluster_size,
                      float* __restrict__ out_loss, float* __restrict__ out_perp,
                      float* __restrict__ out_used) {
  int tid = threadIdx.x;
  float v = 0.0f;
  float used = 0.0f;
  if (tid < 32) {
    float p = stats[1 + tid] * (1.0f / 65536.0f);
    v = p * logf(p + 1e-10f);
    used = (cluster_size[tid] > 1e-5f) ? 1.0f : 0.0f;
  }
  for (int o = 16; o; o >>= 1) { v += __shfl_down(v, o); used += __shfl_down(used, o); }
  if (tid == 0) {
    *out_perp = expf(-v);
    *out_used = used * (1.0f / 32.0f);
    *out_loss = 0.25f * stats[0] * (1.0f / 1048576.0f);
  }
}

// ============ deconv1 strip — templated store target ============
template <int PADDED>
__global__ __launch_bounds__(256) void deconv1_t(
    const float* __restrict__ q, const float* __restrict__ w,
    const float* __restrict__ bias, float* __restrict__ d1) {
  int bid = blockIdx.x;
  int cog = bid & 1;
  int ph  = (bid >> 1) & 1;
  int od  = (bid >> 2) & 7;
  int n   = bid >> 5;
  int tid = threadIdx.x;
  int g   = tid & 7;
  int bl  = tid >> 3;
  bool glf = (g > 0), grf = (g < 7);

  int kd0 = (od + 1) & 1;
  int idtop = (od + 1 - kd0) >> 1;
  int kh0 = (ph + 1) & 1;
  int ihtop = bl + ph;

  float acc[4][8];
  #pragma unroll
  for (int co = 0; co < 4; co++) {
    float bv = bias[cog * 4 + co];
    #pragma unroll
    for (int m = 0; m < 8; m++) acc[co][m] = bv;
  }

  #pragma unroll 1
  for (int ci = 0; ci < 16; ci++) {
    const float* ip = q + ((n * 16 + ci) * 4) * 1024;
    #pragma unroll
    for (int jd = 0; jd < 2; jd++) {
      int id = idtop - jd;
      bool vd = (unsigned)id < 4u;
      int idc = vd ? id : 0;
      const float* plane = ip + idc * 1024;
      #pragma unroll
      for (int jh = 0; jh < 2; jh++) {
        int ih = ihtop - jh;
        bool v = vd && ((unsigned)ih < 32u);
        int ihc = (unsigned)ih < 32u ? ih : 0;
        const float* rp = plane + ihc * 32 + 4 * g;
        float r[6];
        float4 A = ld4(rp);
        float rl = rp[-1 * (int)glf];
        float rr = rp[grf ? 4 : 0];
        r[0] = (v && glf) ? rl : 0.0f;
        r[1] = v ? A.x : 0.0f; r[2] = v ? A.y : 0.0f;
        r[3] = v ? A.z : 0.0f; r[4] = v ? A.w : 0.0f;
        r[5] = (v && grf) ? rr : 0.0f;
        int kd = kd0 + 2 * jd;
        int kh = kh0 + 2 * jh;
        #pragma unroll
        for (int co = 0; co < 4; co++) {
          const float* wb = w + ((ci * 8 + cog * 4 + co) * 4 + kd) * 16 + kh * 4;
          #pragma unroll
          for (int jw = 0; jw < 2; jw++) {
            float w_ev = wb[1 + 2 * jw];
            float w_od = wb[2 * jw];
            #pragma unroll
            for (int ii = 0; ii < 4; ii++) {
              acc[co][2 * ii]     += r[ii + 1 - jw] * w_ev;
              acc[co][2 * ii + 1] += r[ii + 2 - jw] * w_od;
            }
          }
        }
      }
    }
  }
  int oh = 2 * bl + ph;
  #pragma unroll
  for (int co = 0; co < 4; co++) {
    float* op;
    if (PADDED)
      op = d1 + (size_t)(n * 8 + cog * 4 + co) * D1_VOL +
           (od + 1) * D1_PLANE + (oh + 1) * D1_STRIDE + 8 * g + 4;
    else
      op = d1 + ((n * 8 + cog * 4 + co) * 8 + od) * 4096 + oh * 64 + 8 * g;
    float4 lo, hi;
    lo.x = fmaxf(acc[co][0], 0.0f); lo.y = fmaxf(acc[co][1], 0.0f);
    lo.z = fmaxf(acc[co][2], 0.0f); lo.w = fmaxf(acc[co][3], 0.0f);
    hi.x = fmaxf(acc[co][4], 0.0f); hi.y = fmaxf(acc[co][5], 0.0f);
    hi.z = fmaxf(acc[co][6], 0.0f); hi.w = fmaxf(acc[co][7], 0.0f);
    st4(op, lo); st4(op + 4, hi);
  }
}

// ============ deconv3 narrow strip (fallback tiers B/C) ============
template <int INP, int OUTP>
__global__ __launch_bounds__(256) void deconv3_t(
    const float* __restrict__ d1, const float* __restrict__ w,
    const float* __restrict__ bias, float* __restrict__ d2) {
  int bid = blockIdx.x;
  int ph  = bid & 1;
  int blh = (bid >> 1) & 3;
  int od  = (bid >> 3) & 15;
  int n   = bid >> 7;
  int tid = threadIdx.x;
  int g   = tid & 15;
  int bl  = tid >> 4;
  int BL  = blh * 16 + bl;
  bool glf = (g > 0), grf = (g < 15);

  int kd0 = (od + 1) & 1;
  int idtop = (od + 1 - kd0) >> 1;
  int kh0 = (ph + 1) & 1;
  int ihtop = BL + ph;

  float acc[4][8];
  #pragma unroll
  for (int co = 0; co < 4; co++) {
    float bv = bias[co];
    #pragma unroll
    for (int m = 0; m < 8; m++) acc[co][m] = bv;
  }

  #pragma unroll 1
  for (int ci = 0; ci < 8; ci++) {
    #pragma unroll
    for (int jd = 0; jd < 2; jd++) {
      #pragma unroll
      for (int jh = 0; jh < 2; jh++) {
        float r[6];
        if (INP) {
          const float* rp = d1 + (size_t)(n * 8 + ci) * D1_VOL +
                            (idtop + 1 - jd) * D1_PLANE + (ihtop + 1 - jh) * D1_STRIDE +
                            4 * g + 4;
          float4 A = ld4(rp);
          r[0] = rp[-1];
          r[1] = A.x; r[2] = A.y; r[3] = A.z; r[4] = A.w;
          r[5] = rp[4];
        } else {
          const float* ip = d1 + ((n * 8 + ci) * 8) * 4096;
          int id = idtop - jd;
          bool vd = (unsigned)id < 8u;
          int idc = vd ? id : 0;
          const float* plane = ip + idc * 4096;
          int ih = ihtop - jh;
          bool v = vd && ((unsigned)ih < 64u);
          int ihc = (unsigned)ih < 64u ? ih : 0;
          const float* rp = plane + ihc * 64 + 4 * g;
          float4 A = ld4(rp);
          float rl = rp[-1 * (int)glf];
          float rr = rp[grf ? 4 : 0];
          r[0] = (v && glf) ? rl : 0.0f;
          r[1] = v ? A.x : 0.0f; r[2] = v ? A.y : 0.0f;
          r[3] = v ? A.z : 0.0f; r[4] = v ? A.w : 0.0f;
          r[5] = (v && grf) ? rr : 0.0f;
        }
        int kd = kd0 + 2 * jd;
        int kh = kh0 + 2 * jh;
        #pragma unroll
        for (int co = 0; co < 4; co++) {
          const float* wb = w + ((ci * 4 + co) * 4 + kd) * 16 + kh * 4;
          #pragma unroll
          for (int jw = 0; jw < 2; jw++) {
            float w_ev = wb[1 + 2 * jw];
            float w_od = wb[2 * jw];
            #pragma unroll
            for (int ii = 0; ii < 4; ii++) {
              acc[co][2 * ii]     += r[ii + 1 - jw] * w_ev;
              acc[co][2 * ii + 1] += r[ii + 2 - jw] * w_od;
            }
          }
        }
      }
    }
  }
  int oh = 2 * BL + ph;
  #pragma unroll
  for (int co = 0; co < 4; co++) {
    float* op;
    if (OUTP)
      op = d2 + (size_t)(n * 4 + co) * P_VOL + (od + 1) * P_PLANE + (oh + 1) * P_STRIDE + 8 * g + 4;
    else
      op = d2 + ((n * 4 + co) * 16 + od) * 16384 + oh * 128 + 8 * g;
    float4 lo, hi;
    lo.x = fmaxf(acc[co][0], 0.0f); lo.y = fmaxf(acc[co][1], 0.0f);
    lo.z = fmaxf(acc[co][2], 0.0f); lo.w = fmaxf(acc[co][3], 0.0f);
    hi.x = fmaxf(acc[co][4], 0.0f); hi.y = fmaxf(acc[co][5], 0.0f);
    hi.z = fmaxf(acc[co][6], 0.0f); hi.w = fmaxf(acc[co][7], 0.0f);
    st4(op, lo); st4(op + 4, hi);
  }
}

// ============ deconv3 wide strip (tier A: padded in + out) ============
// Thread = 4 co x 16 ow (ow = 16g+m); r[10] = input cols 8g-1..8g+8 loaded
// unconditionally from padded d1p. Same even/odd algebra, ii extended 0..7.
// Grid: ph(2) x blh(2) x od(16) x n(16) = 1024 blocks; block = g(8) x bl(32).
__global__ __launch_bounds__(256) void deconv3w_k(
    const float* __restrict__ d1p, const float* __restrict__ w,
    const float* __restrict__ bias, float* __restrict__ d2p) {
  int bid = blockIdx.x;
  int ph  = bid & 1;
  int blh = (bid >> 1) & 1;
  int od  = (bid >> 2) & 15;
  int n   = bid >> 6;
  int tid = threadIdx.x;
  int g   = tid & 7;        // ow strip 16g..16g+15; input cols 8g-1..8g+8
  int bl  = tid >> 3;       // 0..31
  int BL  = blh * 32 + bl;  // oh = 2*BL + ph

  int kd0 = (od + 1) & 1;
  int idtop = (od + 1 - kd0) >> 1;
  int kh0 = (ph + 1) & 1;
  int ihtop = BL + ph;

  float acc[4][16];
  #pragma unroll
  for (int co = 0; co < 4; co++) {
    float bv = bias[co];
    #pragma unroll
    for (int m = 0; m < 16; m++) acc[co][m] = bv;
  }

  #pragma unroll 1
  for (int ci = 0; ci < 8; ci++) {
    #pragma unroll
    for (int jd = 0; jd < 2; jd++) {
      #pragma unroll
      for (int jh = 0; jh < 2; jh++) {
        // padded base at col 8g+4 (= orig col 8g); r[0]=col 8g-1, r[9]=col 8g+8
        const float* rp = d1p + (size_t)(n * 8 + ci) * D1_VOL +
                          (idtop + 1 - jd) * D1_PLANE + (ihtop + 1 - jh) * D1_STRIDE +
                          8 * g + 4;
        float r[10];
        float4 A = ld4(rp);
        float4 B = ld4(rp + 4);
        r[0] = rp[-1];
        r[1] = A.x; r[2] = A.y; r[3] = A.z; r[4] = A.w;
        r[5] = B.x; r[6] = B.y; r[7] = B.z; r[8] = B.w;
        r[9] = rp[8];
        int kd = kd0 + 2 * jd;
        int kh = kh0 + 2 * jh;
        #pragma unroll
        for (int co = 0; co < 4; co++) {
          const float* wb = w + ((ci * 4 + co) * 4 + kd) * 16 + kh * 4;
          #pragma unroll
          for (int jw = 0; jw < 2; jw++) {
            float w_ev = wb[1 + 2 * jw];
            float w_od = wb[2 * jw];
            #pragma unroll
            for (int ii = 0; ii < 8; ii++) {
              acc[co][2 * ii]     += r[ii + 1 - jw] * w_ev;
              acc[co][2 * ii + 1] += r[ii + 2 - jw] * w_od;
            }
          }
        }
      }
    }
  }
  int oh = 2 * BL + ph;
  #pragma unroll
  for (int co = 0; co < 4; co++) {
    float* op = d2p + (size_t)(n * 4 + co) * P_VOL +
                (od + 1) * P_PLANE + (oh + 1) * P_STRIDE + 16 * g + 4;
    #pragma unroll
    for (int qd = 0; qd < 4; qd++) {
      float4 o;
      o.x = fmaxf(acc[co][4 * qd], 0.0f);
      o.y = fmaxf(acc[co][4 * qd + 1], 0.0f);
      o.z = fmaxf(acc[co][4 * qd + 2], 0.0f);
      o.w = fmaxf(acc[co][4 * qd + 3], 0.0f);
      st4(op + 4 * qd, o);
    }
  }
}

// zero the read-but-never-written halo of d2p
__global__ __launch_bounds__(256) void zero_halo_k(float* __restrict__ d2p) {
  const int PER = 43808;
  int total = PER * 64;
  for (int i = blockIdx.x * 256 + threadIdx.x; i < total; i += gridDim.x * 256) {
    int nc = i / PER;
    int j = i - nc * PER;
    int elem;
    if (j < 35360) {
      int pd = (j < 17680) ? 0 : 17;
      int off = (j < 17680) ? j : j - 17680;
      elem = pd * P_PLANE + off;
    } else if (j < 39712) {
      int k = j - 35360;
      int pd = 1 + (k / 272);
      int rj = k - (pd - 1) * 272;
      int row = (rj < 136) ? 0 : 129;
      int col = (rj < 136) ? rj : rj - 136;
      elem = pd * P_PLANE + row * P_STRIDE + col;
    } else {
      int k = j - 39712;
      int pd = 1 + (k / 256);
      int rj = k - (pd - 1) * 256;
      int row = 1 + (rj >> 1);
      int col = (rj & 1) ? 132 : 3;
      elem = pd * P_PLANE + row * P_STRIDE + col;
    }
    d2p[(size_t)nc * P_VOL + elem] = 0.0f;
  }
}

// zero the read-but-never-written halo of d1p
__global__ __launch_bounds__(256) void zero_halo_d1p_k(float* __restrict__ d1p) {
  const int PER = 11680;
  int total = PER * 128;
  for (int i = blockIdx.x * 256 + threadIdx.x; i < total; i += gridDim.x * 256) {
    int nc = i / PER;
    int j = i - nc * PER;
    int elem;
    if (j < 9504) {
      int pd = (j < 4752) ? 0 : 9;
      int off = (j < 4752) ? j : j - 4752;
      elem = pd * D1_PLANE + off;
    } else if (j < 10656) {
      int k = j - 9504;
      int pd = 1 + (k / 144);
      int rj = k - (pd - 1) * 144;
      int row = (rj < 72) ? 0 : 65;
      int col = (rj < 72) ? rj : rj - 72;
      elem = pd * D1_PLANE + row * D1_STRIDE + col;
    } else {
      int k = j - 10656;
      int pd = 1 + (k / 128);
      int rj = k - (pd - 1) * 128;
      int row = 1 + (rj >> 1);
      int col = (rj & 1) ? 68 : 3;
      elem = pd * D1_PLANE + row * D1_STRIDE + col;
    }
    d1p[(size_t)nc * D1_VOL + elem] = 0.0f;
  }
}

// ============ deconv4 cube, legacy (verified 78.6us, tier-C fallback) ============
__global__ __launch_bounds__(256) void deconv4_k(
    const float* __restrict__ d2, const float* __restrict__ w,
    const float* __restrict__ bias, float* __restrict__ out) {
  int idx = blockIdx.x * 256 + threadIdx.x;
  int c = idx & 63;
  int b = (idx >> 6) & 63;
  int a = (idx >> 12) & 7;
  int n = idx >> 15;
  float acc[2][2][2][3];
  #pragma unroll
  for (int pd = 0; pd < 2; pd++)
    #pragma unroll
    for (int ph = 0; ph < 2; ph++)
      #pragma unroll
      for (int pw = 0; pw < 2; pw++)
        #pragma unroll
        for (int co = 0; co < 3; co++) acc[pd][ph][pw][co] = bias[co];
  int ih0 = 2 * b - 1, iw0 = 2 * c - 1;
  bool vh[4], vw[4];
  #pragma unroll
  for (int l = 0; l < 4; l++) {
    vh[l] = (unsigned)(ih0 + l) < 128u;
    vw[l] = (unsigned)(iw0 + l) < 128u;
  }
  #pragma unroll 1
  for (int ci = 0; ci < 4; ci++) {
    const float* ip = d2 + ((n * 4 + ci) * 16) * 16384;
    #pragma unroll
    for (int ld = 0; ld < 4; ld++) {
      int id = 2 * a - 1 + ld;
      bool vdl = (unsigned)id < 16u;
      const float* pp = ip + id * 16384;
      float p[4][4];
      #pragma unroll
      for (int lh = 0; lh < 4; lh++)
        #pragma unroll
        for (int lw = 0; lw < 4; lw++)
          p[lh][lw] = (vdl && vh[lh] && vw[lw]) ? pp[(ih0 + lh) * 128 + (iw0 + lw)] : 0.0f;
      #pragma unroll
      for (int pd = 0; pd < 2; pd++) {
        int kd = pd + 2 - ld;
        if (kd < 0 || kd > 2) continue;
        #pragma unroll
        for (int kh = 0; kh < 3; kh++)
          #pragma unroll
          for (int kw = 0; kw < 3; kw++)
            #pragma unroll
            for (int co = 0; co < 3; co++) {
              float wv = w[(ci * 3 + co) * 27 + kd * 9 + kh * 3 + kw];
              #pragma unroll
              for (int ph = 0; ph < 2; ph++)
                #pragma unroll
                for (int pw = 0; pw < 2; pw++)
                  acc[pd][ph][pw][co] += p[ph + 2 - kh][pw + 2 - kw] * wv;
            }
      }
    }
  }
  #pragma unroll
  for (int co = 0; co < 3; co++)
    #pragma unroll
    for (int pd = 0; pd < 2; pd++)
      #pragma unroll
      for (int ph = 0; ph < 2; ph++)
        #pragma unroll
        for (int pw = 0; pw < 2; pw++)
          out[((n * 3 + co) * 16 + 2 * a + pd) * 16384 +
              (2 * b + ph) * 128 + (2 * c + pw)] = acc[pd][ph][pw][co];
}

// ============ deconv4 wide cube, padded input (trimmed loads) ============
// Thread = 2(d) x 2(h) x 4(w) x 3 co; loads exactly the 6 used cols per row:
// dword(col3) + dwordx4(cols4..7) + dword(col8) = 24B. 1024 blocks x 256.
__global__ __launch_bounds__(256) void deconv4p_k(
    const float* __restrict__ d2p, const float* __restrict__ w,
    const float* __restrict__ bias, float* __restrict__ out) {
  int idx = blockIdx.x * 256 + threadIdx.x;
  int c = idx & 31;          // ow base 4c
  int b = (idx >> 5) & 63;   // oh base 2b
  int a = (idx >> 11) & 7;   // od base 2a
  int n = idx >> 14;
  float acc[2][2][3][4];     // [pd][ph][co][pw]
  #pragma unroll
  for (int pd = 0; pd < 2; pd++)
    #pragma unroll
    for (int ph = 0; ph < 2; ph++)
      #pragma unroll
      for (int co = 0; co < 3; co++) {
        float bv = bias[co];
        #pragma unroll
        for (int pw = 0; pw < 4; pw++) acc[pd][ph][co][pw] = bv;
      }
  #pragma unroll 1
  for (int ci = 0; ci < 4; ci++) {
    const float* ip = d2p + (size_t)(n * 4 + ci) * P_VOL +
                      (2 * a) * P_PLANE + (2 * b) * P_STRIDE + (4 * c);
    #pragma unroll
    for (int ld = 0; ld < 4; ld++) {
      const float* pp = ip + ld * P_PLANE;
      float rr[4][6];        // cols 4c+3 .. 4c+8 (orig iw 4c-1 .. 4c+4)
      #pragma unroll
      for (int lh = 0; lh < 4; lh++) {
        const float* rp = pp + lh * P_STRIDE;
        float4 A = ld4(rp + 4);
        rr[lh][0] = rp[3];
        rr[lh][1] = A.x; rr[lh][2] = A.y; rr[lh][3] = A.z; rr[lh][4] = A.w;
        rr[lh][5] = rp[8];
      }
      #pragma unroll
      for (int pd = 0; pd < 2; pd++) {
        int kd = pd + 2 - ld;
        if (kd < 0 || kd > 2) continue;
        #pragma unroll
        for (int kh = 0; kh < 3; kh++)
          #pragma unroll
          for (int kw = 0; kw < 3; kw++)
            #pragma unroll
            for (int co = 0; co < 3; co++) {
              float wv = w[(ci * 3 + co) * 27 + kd * 9 + kh * 3 + kw];
              #pragma unroll
              for (int ph = 0; ph < 2; ph++)
                #pragma unroll
                for (int pw = 0; pw < 4; pw++)
                  acc[pd][ph][co][pw] += rr[ph + 2 - kh][pw + 2 - kw] * wv;
            }
      }
    }
  }
  #pragma unroll
  for (int co = 0; co < 3; co++)
    #pragma unroll
    for (int pd = 0; pd < 2; pd++)
      #pragma unroll
      for (int ph = 0; ph < 2; ph++) {
        float4 o;
        o.x = acc[pd][ph][co][0]; o.y = acc[pd][ph][co][1];
        o.z = acc[pd][ph][co][2]; o.w = acc[pd][ph][co][3];
        st4(out + ((n * 3 + co) * 16 + 2 * a + pd) * 16384 +
            (2 * b + ph) * 128 + 4 * c, o);
      }
}

extern "C" void kernel_launch(void* const* d_in, const int* in_sizes, int n_in,
                              void* d_out, int out_size, void* d_ws, size_t ws_size,
                              hipStream_t stream) {
  const float* x      = (const float*)d_in[0];
  const float* enc_w1 = (const float*)d_in[2];
  const float* enc_b1 = (const float*)d_in[3];
  const float* enc_w2 = (const float*)d_in[4];
  const float* enc_b2 = (const float*)d_in[5];
  const float* enc_w4 = (const float*)d_in[6];
  const float* enc_b4 = (const float*)d_in[7];
  const float* dec_w1 = (const float*)d_in[8];
  const float* dec_b1 = (const float*)d_in[9];
  const float* dec_w3 = (const float*)d_in[10];
  const float* dec_b3 = (const float*)d_in[11];
  const float* dec_w4 = (const float*)d_in[12];
  const float* dec_b4 = (const float*)d_in[13];
  const float* emb    = (const float*)d_in[14];
  const float* csize  = (const float*)d_in[15];

  float* ws = (float*)d_ws;
  float* stats = ws;                      // 64
  float* quant = ws + 64;                 // 1,048,576
  float* z     = quant + 1048576;         // 1,048,576
  float* y2    = z + 1048576;             // 524,288
  float* y1    = y2 + 524288;             // 2,097,152 (dead after conv2)

  float* out   = (float*)d_out;                        // 12,582,912
  float* out_loss  = out + 12582912;
  float* out_codes = out_loss + 1;                     // 65,536
  float* out_perp  = out_codes + 65536;
  float* out_used  = out_perp + 1;

  // Tier A (full pad): d1p (6,082,560) + d2p (20,367,360)
  const size_t FULL_NEED = (size_t)(64 + 1048576 + 6082560 + 20367360) * sizeof(float);
  // Tier B: legacy d1 (4,194,304) + d2p
  const size_t MID_NEED  = (size_t)(64 + 1048576 + 4194304 + 20367360) * sizeof(float);

  init_stats_k<<<1, 64, 0, stream>>>(stats);

  conv1_k<<<512, 256, 0, stream>>>(x, enc_w1, enc_b1, y1);
  conv2_k<<<512, 256, 0, stream>>>(y1, enc_w2, enc_b2, y2);
  conv4_k<<<1024, 256, 0, stream>>>(y2, enc_w4, enc_b4, z);

  vq_k<<<256, 256, 0, stream>>>(z, emb, quant, out_codes, stats);
  fin_k<<<1, 64, 0, stream>>>(stats, csize, out_loss, out_perp, out_used);

  if (ws_size >= FULL_NEED) {
    float* d1p = ws + 64 + 1048576;                  // overlaps dead z/y2/y1
    float* d2p = d1p + 6082560;
    zero_halo_k<<<1024, 256, 0, stream>>>(d2p);
    zero_halo_d1p_k<<<1024, 256, 0, stream>>>(d1p);  // after vq_k: z now dead
    deconv1_t<1><<<512, 256, 0, stream>>>(quant, dec_w1, dec_b1, d1p);
    deconv3w_k<<<1024, 256, 0, stream>>>(d1p, dec_w3, dec_b3, d2p);
    deconv4p_k<<<1024, 256, 0, stream>>>(d2p, dec_w4, dec_b4, out);
  } else if (ws_size >= MID_NEED) {
    float* d1  = ws + 64 + 1048576;
    float* d2p = d1 + 4194304;
    zero_halo_k<<<1024, 256, 0, stream>>>(d2p);
    deconv1_t<0><<<512, 256, 0, stream>>>(quant, dec_w1, dec_b1, d1);
    deconv3_t<0, 1><<<2048, 256, 0, stream>>>(d1, dec_w3, dec_b3, d2p);
    deconv4p_k<<<1024, 256, 0, stream>>>(d2p, dec_w4, dec_b4, out);
  } else {
    float* d1 = ws + 64 + 1048576;
    float* d2 = d1 + 4194304;
    deconv1_t<0><<<512, 256, 0, stream>>>(quant, dec_w1, dec_b1, d1);
    deconv3_t<0, 0><<<2048, 256, 0, stream>>>(d1, dec_w3, dec_b3, d2);
    deconv4_k<<<2048, 256, 0, stream>>>(d2, dec_w4, dec_b4, out);
  }
}

// Round 11
// 356.993 us; speedup vs baseline: 1.0021x; 1.0021x over previous
//
#include <hip/hip_runtime.h>
#include <math.h>

#define NB 16

// ---------------- shapes ----------------
// x:      (16, 3,16,128,128)
// y1:     (16, 4, 8, 64, 64)   conv1 k4 s2 p1 + relu
// y2:     (16, 8, 4, 32, 32)   conv2 k4 s2 p1 + relu
// z:      (16,16, 4, 32, 32)   conv4 k3 s1 p1 + clip(0,6)
// quant:  (16,16, 4, 32, 32)   VQ
// d1:     (16, 8, 8, 64, 64)   deconv1 k4 s2 p1 + relu  (padded: [10][66][72])
// d2:     (16, 4,16,128,128)   deconv3 k4 s2 p1 + relu  (padded: [18][130][136])
// out:    (16, 3,16,128,128)   deconv4 k3 s1 p1

// padded d2 geometry
#define P_STRIDE 136              // col = iw + 4; 16B-aligned rows
#define P_PLANE  (130 * P_STRIDE) // row = ih + 1
#define P_VOL    (18 * P_PLANE)   // plane = id + 1
// padded d1 geometry
#define D1_STRIDE 72              // col = iw + 4
#define D1_PLANE  (66 * D1_STRIDE)
#define D1_VOL    (10 * D1_PLANE)

__device__ __forceinline__ float4 ld4(const float* p) {
  return *reinterpret_cast<const float4*>(p);
}
__device__ __forceinline__ void st4(float* p, float4 v) {
  *reinterpret_cast<float4*>(p) = v;
}

// conv1 (R4 strip, measured fast): thread = 4 co x (1 od, 1 oh, 4 ow). 512 blocks.
__global__ __launch_bounds__(256) void conv1_k(
    const float* __restrict__ x, const float* __restrict__ w,
    const float* __restrict__ bias, float* __restrict__ y) {
  int idx = blockIdx.x * 256 + threadIdx.x;
  int g  = idx & 15;
  int oh = (idx >> 4) & 63;
  int od = (idx >> 10) & 7;
  int n  = idx >> 13;
  bool gl = (g > 0), gr = (g < 15);
  float acc[4][4];
  #pragma unroll
  for (int co = 0; co < 4; co++) {
    float bv = bias[co];
    #pragma unroll
    for (int m = 0; m < 4; m++) acc[co][m] = bv;
  }
  int ih0 = 2 * oh - 1;
  #pragma unroll 1
  for (int ci = 0; ci < 3; ci++) {
    #pragma unroll 1
    for (int kd = 0; kd < 4; kd++) {
      int id = 2 * od - 1 + kd;
      bool vd = (unsigned)id < 16u;
      int idc = vd ? id : 0;
      const float* plane = x + (((n * 3 + ci) * 16 + idc) * 16384);
      #pragma unroll
      for (int kh = 0; kh < 4; kh++) {
        int ih = ih0 + kh;
        bool v = vd && ((unsigned)ih < 128u);
        int ihc = (unsigned)ih < 128u ? ih : 0;
        const float* rp = plane + ihc * 128 + 8 * g;
        float r[10];
        float4 A = ld4(rp);
        float4 B = ld4(rp + 4);
        float rl = rp[-1 * (int)gl];
        float rr = rp[gr ? 8 : 0];
        r[0] = (v && gl) ? rl : 0.0f;
        r[1] = v ? A.x : 0.0f; r[2] = v ? A.y : 0.0f;
        r[3] = v ? A.z : 0.0f; r[4] = v ? A.w : 0.0f;
        r[5] = v ? B.x : 0.0f; r[6] = v ? B.y : 0.0f;
        r[7] = v ? B.z : 0.0f; r[8] = v ? B.w : 0.0f;
        r[9] = (v && gr) ? rr : 0.0f;
        #pragma unroll
        for (int co = 0; co < 4; co++) {
          const float* wb = w + ((co * 3 + ci) * 4 + kd) * 16 + kh * 4;
          #pragma unroll
          for (int kw = 0; kw < 4; kw++) {
            float wv = wb[kw];
            #pragma unroll
            for (int m = 0; m < 4; m++)
              acc[co][m] += r[2 * m + kw] * wv;
          }
        }
      }
    }
  }
  #pragma unroll
  for (int co = 0; co < 4; co++) {
    float4 o;
    o.x = fmaxf(acc[co][0], 0.0f); o.y = fmaxf(acc[co][1], 0.0f);
    o.z = fmaxf(acc[co][2], 0.0f); o.w = fmaxf(acc[co][3], 0.0f);
    st4(y + ((n * 4 + co) * 8 + od) * 4096 + oh * 64 + 4 * g, o);
  }
}

// conv2: thread = 1 pos x 4 co. 512 blocks.
__global__ __launch_bounds__(256) void conv2_k(
    const float* __restrict__ y1, const float* __restrict__ w,
    const float* __restrict__ bias, float* __restrict__ y) {
  int idx = blockIdx.x * 256 + threadIdx.x;
  int ow = idx & 31;
  int oh = (idx >> 5) & 31;
  int od = (idx >> 10) & 3;
  int n = (idx >> 12) & 15;
  int cog = idx >> 16;
  float acc[4];
  #pragma unroll
  for (int co = 0; co < 4; co++) acc[co] = bias[cog * 4 + co];
  int id0 = 2 * od - 1, ih0 = 2 * oh - 1, iw0 = 2 * ow - 1;
  bool vh[4], vw[4];
  #pragma unroll
  for (int l = 0; l < 4; l++) {
    vh[l] = (unsigned)(ih0 + l) < 64u;
    vw[l] = (unsigned)(iw0 + l) < 64u;
  }
  #pragma unroll 1
  for (int ci = 0; ci < 4; ci++) {
    const float* ip = y1 + ((n * 4 + ci) * 8) * 4096;
    #pragma unroll
    for (int kd = 0; kd < 4; kd++) {
      int id = id0 + kd;
      bool vd = (unsigned)id < 8u;
      const float* pp = ip + id * 4096;
      float p[4][4];
      #pragma unroll
      for (int kh = 0; kh < 4; kh++)
        #pragma unroll
        for (int kw = 0; kw < 4; kw++)
          p[kh][kw] = (vd && vh[kh] && vw[kw]) ? pp[(ih0 + kh) * 64 + (iw0 + kw)] : 0.0f;
      #pragma unroll
      for (int co = 0; co < 4; co++) {
        const float* wp = w + (((cog * 4 + co) * 4 + ci) * 4 + kd) * 16;
        #pragma unroll
        for (int kh = 0; kh < 4; kh++)
          #pragma unroll
          for (int kw = 0; kw < 4; kw++)
            acc[co] += p[kh][kw] * wp[kh * 4 + kw];
      }
    }
  }
  #pragma unroll
  for (int co = 0; co < 4; co++)
    y[((n * 8 + cog * 4 + co) * 4 + od) * 1024 + oh * 32 + ow] = fmaxf(acc[co], 0.0f);
}

// conv4: thread = 1 pos x 4 co. 1024 blocks.
__global__ __launch_bounds__(256) void conv4_k(
    const float* __restrict__ y2, const float* __restrict__ w,
    const float* __restrict__ bias, float* __restrict__ z) {
  int idx = blockIdx.x * 256 + threadIdx.x;
  int ow = idx & 31;
  int oh = (idx >> 5) & 31;
  int od = (idx >> 10) & 3;
  int n = (idx >> 12) & 15;
  int cog = idx >> 16;
  float acc[4];
  #pragma unroll
  for (int co = 0; co < 4; co++) acc[co] = bias[cog * 4 + co];
  bool vh[3], vw[3];
  #pragma unroll
  for (int l = 0; l < 3; l++) {
    vh[l] = (unsigned)(oh - 1 + l) < 32u;
    vw[l] = (unsigned)(ow - 1 + l) < 32u;
  }
  #pragma unroll 1
  for (int ci = 0; ci < 8; ci++) {
    const float* ip = y2 + ((n * 8 + ci) * 4) * 1024;
    #pragma unroll
    for (int kd = 0; kd < 3; kd++) {
      int id = od - 1 + kd;
      bool vd = (unsigned)id < 4u;
      const float* pp = ip + id * 1024;
      float p[3][3];
      #pragma unroll
      for (int kh = 0; kh < 3; kh++)
        #pragma unroll
        for (int kw = 0; kw < 3; kw++)
          p[kh][kw] = (vd && vh[kh] && vw[kw]) ? pp[(oh - 1 + kh) * 32 + (ow - 1 + kw)] : 0.0f;
      #pragma unroll
      for (int co = 0; co < 4; co++) {
        const float* wp = w + (((cog * 4 + co) * 8 + ci) * 3 + kd) * 9;
        #pragma unroll
        for (int kh = 0; kh < 3; kh++)
          #pragma unroll
          for (int kw = 0; kw < 3; kw++)
            acc[co] += p[kh][kw] * wp[kh * 3 + kw];
      }
    }
  }
  #pragma unroll
  for (int co = 0; co < 4; co++)
    z[((n * 16 + cog * 4 + co) * 4 + od) * 1024 + oh * 32 + ow] =
        fminf(fmaxf(acc[co], 0.0f), 6.0f);
}

// VQ (verified)
__global__ __launch_bounds__(256) void vq_k(
    const float* __restrict__ z, const float* __restrict__ emb,
    float* __restrict__ quant, float* __restrict__ codes_out,
    float* __restrict__ stats) {
  __shared__ float se[32 * 16];
  __shared__ float se2[32];
  __shared__ float shist[32];
  __shared__ float swred[4];
  int tid = threadIdx.x;
  for (int i = tid; i < 512; i += 256) {
    int r = i >> 4;
    float v = emb[i];
    if (r == 0) v = 0.0f;
    else if (r == 1) v = 6.0f;
    se[i] = v;
  }
  if (tid < 32) shist[tid] = 0.0f;
  __syncthreads();
  if (tid < 32) {
    float s = 0.0f;
    #pragma unroll
    for (int d = 0; d < 16; d++) { float v = se[tid * 16 + d]; s += v * v; }
    se2[tid] = s;
  }
  __syncthreads();

  int idx = blockIdx.x * 256 + tid;
  float lsum = 0.0f;
  {
    int w_ = idx & 31; int t = idx >> 5;
    int h_ = t & 31; t >>= 5;
    int d_ = t & 3;  int b_ = t >> 2;
    const float* zp = z + b_ * 65536 + d_ * 1024 + h_ * 32 + w_;
    float f[16];
    float f2 = 0.0f;
    #pragma unroll
    for (int c = 0; c < 16; c++) { float v = zp[c * 4096]; f[c] = v; f2 += v * v; }
    float best = 1e30f; int bi = 0;
    for (int e = 0; e < 32; e++) {
      float dot = 0.0f;
      #pragma unroll
      for (int c = 0; c < 16; c++) dot += f[c] * se[e * 16 + c];
      float d2 = f2 - 2.0f * dot + se2[e];
      if (d2 < best) { best = d2; bi = e; }
    }
    float* qp = quant + b_ * 65536 + d_ * 1024 + h_ * 32 + w_;
    #pragma unroll
    for (int c = 0; c < 16; c++) {
      float q = se[bi * 16 + c];
      qp[c * 4096] = q;
      float df = q - f[c];
      lsum += df * df;
    }
    codes_out[idx] = (float)bi;
    atomicAdd(&shist[bi], 1.0f);
  }
  for (int o = 32; o; o >>= 1) lsum += __shfl_down(lsum, o);
  if ((tid & 63) == 0) swred[tid >> 6] = lsum;
  __syncthreads();
  if (tid == 0) atomicAdd(&stats[0], swred[0] + swred[1] + swred[2] + swred[3]);
  if (tid < 32) {
    float h = shist[tid];
    if (h != 0.0f) atomicAdd(&stats[1 + tid], h);
  }
}

__global__ void init_stats_k(float* __restrict__ stats) {
  int tid = threadIdx.x;
  if (tid < 33) stats[tid] = 0.0f;
}

__global__ void fin_k(const float* __restrict__ stats,
                      const float* __restrict__ cluster_size,
                      float* __restrict__ out_loss, float* __restrict__ out_perp,
                      float* __restrict__ out_used) {
  int tid = threadIdx.x;
  float v = 0.0f;
  float used = 0.0f;
  if (tid < 32) {
    float p = stats[1 + tid] * (1.0f / 65536.0f);
    v = p * logf(p + 1e-10f);
    used = (cluster_size[tid] > 1e-5f) ? 1.0f : 0.0f;
  }
  for (int o = 16; o; o >>= 1) { v += __shfl_down(v, o); used += __shfl_down(used, o); }
  if (tid == 0) {
    *out_perp = expf(-v);
    *out_used = used * (1.0f / 32.0f);
    *out_loss = 0.25f * stats[0] * (1.0f / 1048576.0f);
  }
}

// ============ deconv1 strip — templated store target ============
template <int PADDED>
__global__ __launch_bounds__(256) void deconv1_t(
    const float* __restrict__ q, const float* __restrict__ w,
    const float* __restrict__ bias, float* __restrict__ d1) {
  int bid = blockIdx.x;
  int cog = bid & 1;
  int ph  = (bid >> 1) & 1;
  int od  = (bid >> 2) & 7;
  int n   = bid >> 5;
  int tid = threadIdx.x;
  int g   = tid & 7;
  int bl  = tid >> 3;
  bool glf = (g > 0), grf = (g < 7);

  int kd0 = (od + 1) & 1;
  int idtop = (od + 1 - kd0) >> 1;
  int kh0 = (ph + 1) & 1;
  int ihtop = bl + ph;

  float acc[4][8];
  #pragma unroll
  for (int co = 0; co < 4; co++) {
    float bv = bias[cog * 4 + co];
    #pragma unroll
    for (int m = 0; m < 8; m++) acc[co][m] = bv;
  }

  #pragma unroll 1
  for (int ci = 0; ci < 16; ci++) {
    const float* ip = q + ((n * 16 + ci) * 4) * 1024;
    #pragma unroll
    for (int jd = 0; jd < 2; jd++) {
      int id = idtop - jd;
      bool vd = (unsigned)id < 4u;
      int idc = vd ? id : 0;
      const float* plane = ip + idc * 1024;
      #pragma unroll
      for (int jh = 0; jh < 2; jh++) {
        int ih = ihtop - jh;
        bool v = vd && ((unsigned)ih < 32u);
        int ihc = (unsigned)ih < 32u ? ih : 0;
        const float* rp = plane + ihc * 32 + 4 * g;
        float r[6];
        float4 A = ld4(rp);
        float rl = rp[-1 * (int)glf];
        float rr = rp[grf ? 4 : 0];
        r[0] = (v && glf) ? rl : 0.0f;
        r[1] = v ? A.x : 0.0f; r[2] = v ? A.y : 0.0f;
        r[3] = v ? A.z : 0.0f; r[4] = v ? A.w : 0.0f;
        r[5] = (v && grf) ? rr : 0.0f;
        int kd = kd0 + 2 * jd;
        int kh = kh0 + 2 * jh;
        #pragma unroll
        for (int co = 0; co < 4; co++) {
          const float* wb = w + ((ci * 8 + cog * 4 + co) * 4 + kd) * 16 + kh * 4;
          #pragma unroll
          for (int jw = 0; jw < 2; jw++) {
            float w_ev = wb[1 + 2 * jw];
            float w_od = wb[2 * jw];
            #pragma unroll
            for (int ii = 0; ii < 4; ii++) {
              acc[co][2 * ii]     += r[ii + 1 - jw] * w_ev;
              acc[co][2 * ii + 1] += r[ii + 2 - jw] * w_od;
            }
          }
        }
      }
    }
  }
  int oh = 2 * bl + ph;
  #pragma unroll
  for (int co = 0; co < 4; co++) {
    float* op;
    if (PADDED)
      op = d1 + (size_t)(n * 8 + cog * 4 + co) * D1_VOL +
           (od + 1) * D1_PLANE + (oh + 1) * D1_STRIDE + 8 * g + 4;
    else
      op = d1 + ((n * 8 + cog * 4 + co) * 8 + od) * 4096 + oh * 64 + 8 * g;
    float4 lo, hi;
    lo.x = fmaxf(acc[co][0], 0.0f); lo.y = fmaxf(acc[co][1], 0.0f);
    lo.z = fmaxf(acc[co][2], 0.0f); lo.w = fmaxf(acc[co][3], 0.0f);
    hi.x = fmaxf(acc[co][4], 0.0f); hi.y = fmaxf(acc[co][5], 0.0f);
    hi.z = fmaxf(acc[co][6], 0.0f); hi.w = fmaxf(acc[co][7], 0.0f);
    st4(op, lo); st4(op + 4, hi);
  }
}

// ============ deconv3 narrow strip (fallback tiers B/C) ============
template <int INP, int OUTP>
__global__ __launch_bounds__(256) void deconv3_t(
    const float* __restrict__ d1, const float* __restrict__ w,
    const float* __restrict__ bias, float* __restrict__ d2) {
  int bid = blockIdx.x;
  int ph  = bid & 1;
  int blh = (bid >> 1) & 3;
  int od  = (bid >> 3) & 15;
  int n   = bid >> 7;
  int tid = threadIdx.x;
  int g   = tid & 15;
  int bl  = tid >> 4;
  int BL  = blh * 16 + bl;
  bool glf = (g > 0), grf = (g < 15);

  int kd0 = (od + 1) & 1;
  int idtop = (od + 1 - kd0) >> 1;
  int kh0 = (ph + 1) & 1;
  int ihtop = BL + ph;

  float acc[4][8];
  #pragma unroll
  for (int co = 0; co < 4; co++) {
    float bv = bias[co];
    #pragma unroll
    for (int m = 0; m < 8; m++) acc[co][m] = bv;
  }

  #pragma unroll 1
  for (int ci = 0; ci < 8; ci++) {
    #pragma unroll
    for (int jd = 0; jd < 2; jd++) {
      #pragma unroll
      for (int jh = 0; jh < 2; jh++) {
        float r[6];
        if (INP) {
          const float* rp = d1 + (size_t)(n * 8 + ci) * D1_VOL +
                            (idtop + 1 - jd) * D1_PLANE + (ihtop + 1 - jh) * D1_STRIDE +
                            4 * g + 4;
          float4 A = ld4(rp);
          r[0] = rp[-1];
          r[1] = A.x; r[2] = A.y; r[3] = A.z; r[4] = A.w;
          r[5] = rp[4];
        } else {
          const float* ip = d1 + ((n * 8 + ci) * 8) * 4096;
          int id = idtop - jd;
          bool vd = (unsigned)id < 8u;
          int idc = vd ? id : 0;
          const float* plane = ip + idc * 4096;
          int ih = ihtop - jh;
          bool v = vd && ((unsigned)ih < 64u);
          int ihc = (unsigned)ih < 64u ? ih : 0;
          const float* rp = plane + ihc * 64 + 4 * g;
          float4 A = ld4(rp);
          float rl = rp[-1 * (int)glf];
          float rr = rp[grf ? 4 : 0];
          r[0] = (v && glf) ? rl : 0.0f;
          r[1] = v ? A.x : 0.0f; r[2] = v ? A.y : 0.0f;
          r[3] = v ? A.z : 0.0f; r[4] = v ? A.w : 0.0f;
          r[5] = (v && grf) ? rr : 0.0f;
        }
        int kd = kd0 + 2 * jd;
        int kh = kh0 + 2 * jh;
        #pragma unroll
        for (int co = 0; co < 4; co++) {
          const float* wb = w + ((ci * 4 + co) * 4 + kd) * 16 + kh * 4;
          #pragma unroll
          for (int jw = 0; jw < 2; jw++) {
            float w_ev = wb[1 + 2 * jw];
            float w_od = wb[2 * jw];
            #pragma unroll
            for (int ii = 0; ii < 4; ii++) {
              acc[co][2 * ii]     += r[ii + 1 - jw] * w_ev;
              acc[co][2 * ii + 1] += r[ii + 2 - jw] * w_od;
            }
          }
        }
      }
    }
  }
  int oh = 2 * BL + ph;
  #pragma unroll
  for (int co = 0; co < 4; co++) {
    float* op;
    if (OUTP)
      op = d2 + (size_t)(n * 4 + co) * P_VOL + (od + 1) * P_PLANE + (oh + 1) * P_STRIDE + 8 * g + 4;
    else
      op = d2 + ((n * 4 + co) * 16 + od) * 16384 + oh * 128 + 8 * g;
    float4 lo, hi;
    lo.x = fmaxf(acc[co][0], 0.0f); lo.y = fmaxf(acc[co][1], 0.0f);
    lo.z = fmaxf(acc[co][2], 0.0f); lo.w = fmaxf(acc[co][3], 0.0f);
    hi.x = fmaxf(acc[co][4], 0.0f); hi.y = fmaxf(acc[co][5], 0.0f);
    hi.z = fmaxf(acc[co][6], 0.0f); hi.w = fmaxf(acc[co][7], 0.0f);
    st4(op, lo); st4(op + 4, hi);
  }
}

// ============ deconv3 wide strip (tier A: padded in + out; kept from R10) ============
// Thread = 4 co x 16 ow (ow = 16g+m); r[10] = input cols 8g-1..8g+8 loaded
// unconditionally from padded d1p. Same even/odd algebra, ii extended 0..7.
// Grid: ph(2) x blh(2) x od(16) x n(16) = 1024 blocks; block = g(8) x bl(32).
__global__ __launch_bounds__(256) void deconv3w_k(
    const float* __restrict__ d1p, const float* __restrict__ w,
    const float* __restrict__ bias, float* __restrict__ d2p) {
  int bid = blockIdx.x;
  int ph  = bid & 1;
  int blh = (bid >> 1) & 1;
  int od  = (bid >> 2) & 15;
  int n   = bid >> 6;
  int tid = threadIdx.x;
  int g   = tid & 7;        // ow strip 16g..16g+15; input cols 8g-1..8g+8
  int bl  = tid >> 3;       // 0..31
  int BL  = blh * 32 + bl;  // oh = 2*BL + ph

  int kd0 = (od + 1) & 1;
  int idtop = (od + 1 - kd0) >> 1;
  int kh0 = (ph + 1) & 1;
  int ihtop = BL + ph;

  float acc[4][16];
  #pragma unroll
  for (int co = 0; co < 4; co++) {
    float bv = bias[co];
    #pragma unroll
    for (int m = 0; m < 16; m++) acc[co][m] = bv;
  }

  #pragma unroll 1
  for (int ci = 0; ci < 8; ci++) {
    #pragma unroll
    for (int jd = 0; jd < 2; jd++) {
      #pragma unroll
      for (int jh = 0; jh < 2; jh++) {
        // padded base at col 8g+4 (= orig col 8g); r[0]=col 8g-1, r[9]=col 8g+8
        const float* rp = d1p + (size_t)(n * 8 + ci) * D1_VOL +
                          (idtop + 1 - jd) * D1_PLANE + (ihtop + 1 - jh) * D1_STRIDE +
                          8 * g + 4;
        float r[10];
        float4 A = ld4(rp);
        float4 B = ld4(rp + 4);
        r[0] = rp[-1];
        r[1] = A.x; r[2] = A.y; r[3] = A.z; r[4] = A.w;
        r[5] = B.x; r[6] = B.y; r[7] = B.z; r[8] = B.w;
        r[9] = rp[8];
        int kd = kd0 + 2 * jd;
        int kh = kh0 + 2 * jh;
        #pragma unroll
        for (int co = 0; co < 4; co++) {
          const float* wb = w + ((ci * 4 + co) * 4 + kd) * 16 + kh * 4;
          #pragma unroll
          for (int jw = 0; jw < 2; jw++) {
            float w_ev = wb[1 + 2 * jw];
            float w_od = wb[2 * jw];
            #pragma unroll
            for (int ii = 0; ii < 8; ii++) {
              acc[co][2 * ii]     += r[ii + 1 - jw] * w_ev;
              acc[co][2 * ii + 1] += r[ii + 2 - jw] * w_od;
            }
          }
        }
      }
    }
  }
  int oh = 2 * BL + ph;
  #pragma unroll
  for (int co = 0; co < 4; co++) {
    float* op = d2p + (size_t)(n * 4 + co) * P_VOL +
                (od + 1) * P_PLANE + (oh + 1) * P_STRIDE + 16 * g + 4;
    #pragma unroll
    for (int qd = 0; qd < 4; qd++) {
      float4 o;
      o.x = fmaxf(acc[co][4 * qd], 0.0f);
      o.y = fmaxf(acc[co][4 * qd + 1], 0.0f);
      o.z = fmaxf(acc[co][4 * qd + 2], 0.0f);
      o.w = fmaxf(acc[co][4 * qd + 3], 0.0f);
      st4(op + 4 * qd, o);
    }
  }
}

// zero the read-but-never-written halo of d2p
__global__ __launch_bounds__(256) void zero_halo_k(float* __restrict__ d2p) {
  const int PER = 43808;
  int total = PER * 64;
  for (int i = blockIdx.x * 256 + threadIdx.x; i < total; i += gridDim.x * 256) {
    int nc = i / PER;
    int j = i - nc * PER;
    int elem;
    if (j < 35360) {
      int pd = (j < 17680) ? 0 : 17;
      int off = (j < 17680) ? j : j - 17680;
      elem = pd * P_PLANE + off;
    } else if (j < 39712) {
      int k = j - 35360;
      int pd = 1 + (k / 272);
      int rj = k - (pd - 1) * 272;
      int row = (rj < 136) ? 0 : 129;
      int col = (rj < 136) ? rj : rj - 136;
      elem = pd * P_PLANE + row * P_STRIDE + col;
    } else {
      int k = j - 39712;
      int pd = 1 + (k / 256);
      int rj = k - (pd - 1) * 256;
      int row = 1 + (rj >> 1);
      int col = (rj & 1) ? 132 : 3;
      elem = pd * P_PLANE + row * P_STRIDE + col;
    }
    d2p[(size_t)nc * P_VOL + elem] = 0.0f;
  }
}

// zero the read-but-never-written halo of d1p
__global__ __launch_bounds__(256) void zero_halo_d1p_k(float* __restrict__ d1p) {
  const int PER = 11680;
  int total = PER * 128;
  for (int i = blockIdx.x * 256 + threadIdx.x; i < total; i += gridDim.x * 256) {
    int nc = i / PER;
    int j = i - nc * PER;
    int elem;
    if (j < 9504) {
      int pd = (j < 4752) ? 0 : 9;
      int off = (j < 4752) ? j : j - 4752;
      elem = pd * D1_PLANE + off;
    } else if (j < 10656) {
      int k = j - 9504;
      int pd = 1 + (k / 144);
      int rj = k - (pd - 1) * 144;
      int row = (rj < 72) ? 0 : 65;
      int col = (rj < 72) ? rj : rj - 72;
      elem = pd * D1_PLANE + row * D1_STRIDE + col;
    } else {
      int k = j - 10656;
      int pd = 1 + (k / 128);
      int rj = k - (pd - 1) * 128;
      int row = 1 + (rj >> 1);
      int col = (rj & 1) ? 68 : 3;
      elem = pd * D1_PLANE + row * D1_STRIDE + col;
    }
    d1p[(size_t)nc * D1_VOL + elem] = 0.0f;
  }
}

// ============ deconv4 cube, legacy (verified 78.6us, tier-C fallback) ============
__global__ __launch_bounds__(256) void deconv4_k(
    const float* __restrict__ d2, const float* __restrict__ w,
    const float* __restrict__ bias, float* __restrict__ out) {
  int idx = blockIdx.x * 256 + threadIdx.x;
  int c = idx & 63;
  int b = (idx >> 6) & 63;
  int a = (idx >> 12) & 7;
  int n = idx >> 15;
  float acc[2][2][2][3];
  #pragma unroll
  for (int pd = 0; pd < 2; pd++)
    #pragma unroll
    for (int ph = 0; ph < 2; ph++)
      #pragma unroll
      for (int pw = 0; pw < 2; pw++)
        #pragma unroll
        for (int co = 0; co < 3; co++) acc[pd][ph][pw][co] = bias[co];
  int ih0 = 2 * b - 1, iw0 = 2 * c - 1;
  bool vh[4], vw[4];
  #pragma unroll
  for (int l = 0; l < 4; l++) {
    vh[l] = (unsigned)(ih0 + l) < 128u;
    vw[l] = (unsigned)(iw0 + l) < 128u;
  }
  #pragma unroll 1
  for (int ci = 0; ci < 4; ci++) {
    const float* ip = d2 + ((n * 4 + ci) * 16) * 16384;
    #pragma unroll
    for (int ld = 0; ld < 4; ld++) {
      int id = 2 * a - 1 + ld;
      bool vdl = (unsigned)id < 16u;
      const float* pp = ip + id * 16384;
      float p[4][4];
      #pragma unroll
      for (int lh = 0; lh < 4; lh++)
        #pragma unroll
        for (int lw = 0; lw < 4; lw++)
          p[lh][lw] = (vdl && vh[lh] && vw[lw]) ? pp[(ih0 + lh) * 128 + (iw0 + lw)] : 0.0f;
      #pragma unroll
      for (int pd = 0; pd < 2; pd++) {
        int kd = pd + 2 - ld;
        if (kd < 0 || kd > 2) continue;
        #pragma unroll
        for (int kh = 0; kh < 3; kh++)
          #pragma unroll
          for (int kw = 0; kw < 3; kw++)
            #pragma unroll
            for (int co = 0; co < 3; co++) {
              float wv = w[(ci * 3 + co) * 27 + kd * 9 + kh * 3 + kw];
              #pragma unroll
              for (int ph = 0; ph < 2; ph++)
                #pragma unroll
                for (int pw = 0; pw < 2; pw++)
                  acc[pd][ph][pw][co] += p[ph + 2 - kh][pw + 2 - kw] * wv;
            }
      }
    }
  }
  #pragma unroll
  for (int co = 0; co < 3; co++)
    #pragma unroll
    for (int pd = 0; pd < 2; pd++)
      #pragma unroll
      for (int ph = 0; ph < 2; ph++)
        #pragma unroll
        for (int pw = 0; pw < 2; pw++)
          out[((n * 3 + co) * 16 + 2 * a + pd) * 16384 +
              (2 * b + ph) * 128 + (2 * c + pw)] = acc[pd][ph][pw][co];
}

// ============ deconv4 wide cube, padded input (R9 verified 49.8us form) ============
// Thread = 2(d) x 2(h) x 4(w) x 3 co; 3 fully-coalesced ld4 per row (16B-stride
// lanes, every load instruction 100% utilized). Trimmed-load variant (R10)
// regressed 20%: quarter-width dword issues waste the data path.
__global__ __launch_bounds__(256) void deconv4p_k(
    const float* __restrict__ d2p, const float* __restrict__ w,
    const float* __restrict__ bias, float* __restrict__ out) {
  int idx = blockIdx.x * 256 + threadIdx.x;
  int c = idx & 31;          // ow base 4c
  int b = (idx >> 5) & 63;   // oh base 2b
  int a = (idx >> 11) & 7;   // od base 2a
  int n = idx >> 14;
  float acc[2][2][3][4];     // [pd][ph][co][pw]
  #pragma unroll
  for (int pd = 0; pd < 2; pd++)
    #pragma unroll
    for (int ph = 0; ph < 2; ph++)
      #pragma unroll
      for (int co = 0; co < 3; co++) {
        float bv = bias[co];
        #pragma unroll
        for (int pw = 0; pw < 4; pw++) acc[pd][ph][co][pw] = bv;
      }
  #pragma unroll 1
  for (int ci = 0; ci < 4; ci++) {
    // base at (plane 2a, row 2b, col 4c): window cols 4c+3..4c+8 within 0..11
    const float* ip = d2p + (size_t)(n * 4 + ci) * P_VOL +
                      (2 * a) * P_PLANE + (2 * b) * P_STRIDE + (4 * c);
    #pragma unroll
    for (int ld = 0; ld < 4; ld++) {
      const float* pp = ip + ld * P_PLANE;
      float pr[4][12];
      #pragma unroll
      for (int lh = 0; lh < 4; lh++) {
        const float* rp = pp + lh * P_STRIDE;
        float4 A = ld4(rp);
        float4 B = ld4(rp + 4);
        float4 C = ld4(rp + 8);
        pr[lh][0] = A.x;  pr[lh][1] = A.y;  pr[lh][2] = A.z;  pr[lh][3] = A.w;
        pr[lh][4] = B.x;  pr[lh][5] = B.y;  pr[lh][6] = B.z;  pr[lh][7] = B.w;
        pr[lh][8] = C.x;  pr[lh][9] = C.y;  pr[lh][10] = C.z; pr[lh][11] = C.w;
      }
      #pragma unroll
      for (int pd = 0; pd < 2; pd++) {
        int kd = pd + 2 - ld;
        if (kd < 0 || kd > 2) continue;
        #pragma unroll
        for (int kh = 0; kh < 3; kh++)
          #pragma unroll
          for (int kw = 0; kw < 3; kw++)
            #pragma unroll
            for (int co = 0; co < 3; co++) {
              float wv = w[(ci * 3 + co) * 27 + kd * 9 + kh * 3 + kw];
              #pragma unroll
              for (int ph = 0; ph < 2; ph++)
                #pragma unroll
                for (int pw = 0; pw < 4; pw++)
                  acc[pd][ph][co][pw] += pr[ph + 2 - kh][pw + 5 - kw] * wv;
            }
      }
    }
  }
  #pragma unroll
  for (int co = 0; co < 3; co++)
    #pragma unroll
    for (int pd = 0; pd < 2; pd++)
      #pragma unroll
      for (int ph = 0; ph < 2; ph++) {
        float4 o;
        o.x = acc[pd][ph][co][0]; o.y = acc[pd][ph][co][1];
        o.z = acc[pd][ph][co][2]; o.w = acc[pd][ph][co][3];
        st4(out + ((n * 3 + co) * 16 + 2 * a + pd) * 16384 +
            (2 * b + ph) * 128 + 4 * c, o);
      }
}

extern "C" void kernel_launch(void* const* d_in, const int* in_sizes, int n_in,
                              void* d_out, int out_size, void* d_ws, size_t ws_size,
                              hipStream_t stream) {
  const float* x      = (const float*)d_in[0];
  const float* enc_w1 = (const float*)d_in[2];
  const float* enc_b1 = (const float*)d_in[3];
  const float* enc_w2 = (const float*)d_in[4];
  const float* enc_b2 = (const float*)d_in[5];
  const float* enc_w4 = (const float*)d_in[6];
  const float* enc_b4 = (const float*)d_in[7];
  const float* dec_w1 = (const float*)d_in[8];
  const float* dec_b1 = (const float*)d_in[9];
  const float* dec_w3 = (const float*)d_in[10];
  const float* dec_b3 = (const float*)d_in[11];
  const float* dec_w4 = (const float*)d_in[12];
  const float* dec_b4 = (const float*)d_in[13];
  const float* emb    = (const float*)d_in[14];
  const float* csize  = (const float*)d_in[15];

  float* ws = (float*)d_ws;
  float* stats = ws;                      // 64
  float* quant = ws + 64;                 // 1,048,576
  float* z     = quant + 1048576;         // 1,048,576
  float* y2    = z + 1048576;             // 524,288
  float* y1    = y2 + 524288;             // 2,097,152 (dead after conv2)

  float* out   = (float*)d_out;                        // 12,582,912
  float* out_loss  = out + 12582912;
  float* out_codes = out_loss + 1;                     // 65,536
  float* out_perp  = out_codes + 65536;
  float* out_used  = out_perp + 1;

  // Tier A (full pad): d1p (6,082,560) + d2p (20,367,360)
  const size_t FULL_NEED = (size_t)(64 + 1048576 + 6082560 + 20367360) * sizeof(float);
  // Tier B: legacy d1 (4,194,304) + d2p
  const size_t MID_NEED  = (size_t)(64 + 1048576 + 4194304 + 20367360) * sizeof(float);

  init_stats_k<<<1, 64, 0, stream>>>(stats);

  conv1_k<<<512, 256, 0, stream>>>(x, enc_w1, enc_b1, y1);
  conv2_k<<<512, 256, 0, stream>>>(y1, enc_w2, enc_b2, y2);
  conv4_k<<<1024, 256, 0, stream>>>(y2, enc_w4, enc_b4, z);

  vq_k<<<256, 256, 0, stream>>>(z, emb, quant, out_codes, stats);
  fin_k<<<1, 64, 0, stream>>>(stats, csize, out_loss, out_perp, out_used);

  if (ws_size >= FULL_NEED) {
    float* d1p = ws + 64 + 1048576;                  // overlaps dead z/y2/y1
    float* d2p = d1p + 6082560;
    zero_halo_k<<<1024, 256, 0, stream>>>(d2p);
    zero_halo_d1p_k<<<1024, 256, 0, stream>>>(d1p);  // after vq_k: z now dead
    deconv1_t<1><<<512, 256, 0, stream>>>(quant, dec_w1, dec_b1, d1p);
    deconv3w_k<<<1024, 256, 0, stream>>>(d1p, dec_w3, dec_b3, d2p);
    deconv4p_k<<<1024, 256, 0, stream>>>(d2p, dec_w4, dec_b4, out);
  } else if (ws_size >= MID_NEED) {
    float* d1  = ws + 64 + 1048576;
    float* d2p = d1 + 4194304;
    zero_halo_k<<<1024, 256, 0, stream>>>(d2p);
    deconv1_t<0><<<512, 256, 0, stream>>>(quant, dec_w1, dec_b1, d1);
    deconv3_t<0, 1><<<2048, 256, 0, stream>>>(d1, dec_w3, dec_b3, d2p);
    deconv4p_k<<<1024, 256, 0, stream>>>(d2p, dec_w4, dec_b4, out);
  } else {
    float* d1 = ws + 64 + 1048576;
    float* d2 = d1 + 4194304;
    deconv1_t<0><<<512, 256, 0, stream>>>(quant, dec_w1, dec_b1, d1);
    deconv3_t<0, 0><<<2048, 256, 0, stream>>>(d1, dec_w3, dec_b3, d2);
    deconv4_k<<<2048, 256, 0, stream>>>(d2, dec_w4, dec_b4, out);
  }
}

// Round 12
// 349.822 us; speedup vs baseline: 1.0226x; 1.0205x over previous
//
#include <hip/hip_runtime.h>
#include <math.h>

#define NB 16

// ---------------- shapes ----------------
// x:      (16, 3,16,128,128)
// y1:     (16, 4, 8, 64, 64)   conv1 k4 s2 p1 + relu
// y2:     (16, 8, 4, 32, 32)   conv2 k4 s2 p1 + relu
// z:      (16,16, 4, 32, 32)   conv4 k3 s1 p1 + clip(0,6)
// quant:  (16,16, 4, 32, 32)   VQ
// d1:     (16, 8, 8, 64, 64)   deconv1 k4 s2 p1 + relu  (padded: [10][66][72])
// d2:     (16, 4,16,128,128)   deconv3 k4 s2 p1 + relu  (padded: [18][130][136])
// out:    (16, 3,16,128,128)   deconv4 k3 s1 p1

// padded d2 geometry
#define P_STRIDE 136              // col = iw + 4; 16B-aligned rows
#define P_PLANE  (130 * P_STRIDE) // row = ih + 1
#define P_VOL    (18 * P_PLANE)   // plane = id + 1
// padded d1 geometry
#define D1_STRIDE 72              // col = iw + 4
#define D1_PLANE  (66 * D1_STRIDE)
#define D1_VOL    (10 * D1_PLANE)

__device__ __forceinline__ float4 ld4(const float* p) {
  return *reinterpret_cast<const float4*>(p);
}
__device__ __forceinline__ void st4(float* p, float4 v) {
  *reinterpret_cast<float4*>(p) = v;
}

// conv1 (R4 strip, measured fast): thread = 4 co x (1 od, 1 oh, 4 ow). 512 blocks.
__global__ __launch_bounds__(256) void conv1_k(
    const float* __restrict__ x, const float* __restrict__ w,
    const float* __restrict__ bias, float* __restrict__ y) {
  int idx = blockIdx.x * 256 + threadIdx.x;
  int g  = idx & 15;
  int oh = (idx >> 4) & 63;
  int od = (idx >> 10) & 7;
  int n  = idx >> 13;
  bool gl = (g > 0), gr = (g < 15);
  float acc[4][4];
  #pragma unroll
  for (int co = 0; co < 4; co++) {
    float bv = bias[co];
    #pragma unroll
    for (int m = 0; m < 4; m++) acc[co][m] = bv;
  }
  int ih0 = 2 * oh - 1;
  #pragma unroll 1
  for (int ci = 0; ci < 3; ci++) {
    #pragma unroll 1
    for (int kd = 0; kd < 4; kd++) {
      int id = 2 * od - 1 + kd;
      bool vd = (unsigned)id < 16u;
      int idc = vd ? id : 0;
      const float* plane = x + (((n * 3 + ci) * 16 + idc) * 16384);
      #pragma unroll
      for (int kh = 0; kh < 4; kh++) {
        int ih = ih0 + kh;
        bool v = vd && ((unsigned)ih < 128u);
        int ihc = (unsigned)ih < 128u ? ih : 0;
        const float* rp = plane + ihc * 128 + 8 * g;
        float r[10];
        float4 A = ld4(rp);
        float4 B = ld4(rp + 4);
        float rl = rp[-1 * (int)gl];
        float rr = rp[gr ? 8 : 0];
        r[0] = (v && gl) ? rl : 0.0f;
        r[1] = v ? A.x : 0.0f; r[2] = v ? A.y : 0.0f;
        r[3] = v ? A.z : 0.0f; r[4] = v ? A.w : 0.0f;
        r[5] = v ? B.x : 0.0f; r[6] = v ? B.y : 0.0f;
        r[7] = v ? B.z : 0.0f; r[8] = v ? B.w : 0.0f;
        r[9] = (v && gr) ? rr : 0.0f;
        #pragma unroll
        for (int co = 0; co < 4; co++) {
          const float* wb = w + ((co * 3 + ci) * 4 + kd) * 16 + kh * 4;
          #pragma unroll
          for (int kw = 0; kw < 4; kw++) {
            float wv = wb[kw];
            #pragma unroll
            for (int m = 0; m < 4; m++)
              acc[co][m] += r[2 * m + kw] * wv;
          }
        }
      }
    }
  }
  #pragma unroll
  for (int co = 0; co < 4; co++) {
    float4 o;
    o.x = fmaxf(acc[co][0], 0.0f); o.y = fmaxf(acc[co][1], 0.0f);
    o.z = fmaxf(acc[co][2], 0.0f); o.w = fmaxf(acc[co][3], 0.0f);
    st4(y + ((n * 4 + co) * 8 + od) * 4096 + oh * 64 + 4 * g, o);
  }
}

// conv2: thread = 1 pos x 4 co. 512 blocks.
__global__ __launch_bounds__(256) void conv2_k(
    const float* __restrict__ y1, const float* __restrict__ w,
    const float* __restrict__ bias, float* __restrict__ y) {
  int idx = blockIdx.x * 256 + threadIdx.x;
  int ow = idx & 31;
  int oh = (idx >> 5) & 31;
  int od = (idx >> 10) & 3;
  int n = (idx >> 12) & 15;
  int cog = idx >> 16;
  float acc[4];
  #pragma unroll
  for (int co = 0; co < 4; co++) acc[co] = bias[cog * 4 + co];
  int id0 = 2 * od - 1, ih0 = 2 * oh - 1, iw0 = 2 * ow - 1;
  bool vh[4], vw[4];
  #pragma unroll
  for (int l = 0; l < 4; l++) {
    vh[l] = (unsigned)(ih0 + l) < 64u;
    vw[l] = (unsigned)(iw0 + l) < 64u;
  }
  #pragma unroll 1
  for (int ci = 0; ci < 4; ci++) {
    const float* ip = y1 + ((n * 4 + ci) * 8) * 4096;
    #pragma unroll
    for (int kd = 0; kd < 4; kd++) {
      int id = id0 + kd;
      bool vd = (unsigned)id < 8u;
      const float* pp = ip + id * 4096;
      float p[4][4];
      #pragma unroll
      for (int kh = 0; kh < 4; kh++)
        #pragma unroll
        for (int kw = 0; kw < 4; kw++)
          p[kh][kw] = (vd && vh[kh] && vw[kw]) ? pp[(ih0 + kh) * 64 + (iw0 + kw)] : 0.0f;
      #pragma unroll
      for (int co = 0; co < 4; co++) {
        const float* wp = w + (((cog * 4 + co) * 4 + ci) * 4 + kd) * 16;
        #pragma unroll
        for (int kh = 0; kh < 4; kh++)
          #pragma unroll
          for (int kw = 0; kw < 4; kw++)
            acc[co] += p[kh][kw] * wp[kh * 4 + kw];
      }
    }
  }
  #pragma unroll
  for (int co = 0; co < 4; co++)
    y[((n * 8 + cog * 4 + co) * 4 + od) * 1024 + oh * 32 + ow] = fmaxf(acc[co], 0.0f);
}

// conv4: thread = 1 pos x 4 co. 1024 blocks.
__global__ __launch_bounds__(256) void conv4_k(
    const float* __restrict__ y2, const float* __restrict__ w,
    const float* __restrict__ bias, float* __restrict__ z) {
  int idx = blockIdx.x * 256 + threadIdx.x;
  int ow = idx & 31;
  int oh = (idx >> 5) & 31;
  int od = (idx >> 10) & 3;
  int n = (idx >> 12) & 15;
  int cog = idx >> 16;
  float acc[4];
  #pragma unroll
  for (int co = 0; co < 4; co++) acc[co] = bias[cog * 4 + co];
  bool vh[3], vw[3];
  #pragma unroll
  for (int l = 0; l < 3; l++) {
    vh[l] = (unsigned)(oh - 1 + l) < 32u;
    vw[l] = (unsigned)(ow - 1 + l) < 32u;
  }
  #pragma unroll 1
  for (int ci = 0; ci < 8; ci++) {
    const float* ip = y2 + ((n * 8 + ci) * 4) * 1024;
    #pragma unroll
    for (int kd = 0; kd < 3; kd++) {
      int id = od - 1 + kd;
      bool vd = (unsigned)id < 4u;
      const float* pp = ip + id * 1024;
      float p[3][3];
      #pragma unroll
      for (int kh = 0; kh < 3; kh++)
        #pragma unroll
        for (int kw = 0; kw < 3; kw++)
          p[kh][kw] = (vd && vh[kh] && vw[kw]) ? pp[(oh - 1 + kh) * 32 + (ow - 1 + kw)] : 0.0f;
      #pragma unroll
      for (int co = 0; co < 4; co++) {
        const float* wp = w + (((cog * 4 + co) * 8 + ci) * 3 + kd) * 9;
        #pragma unroll
        for (int kh = 0; kh < 3; kh++)
          #pragma unroll
          for (int kw = 0; kw < 3; kw++)
            acc[co] += p[kh][kw] * wp[kh * 3 + kw];
      }
    }
  }
  #pragma unroll
  for (int co = 0; co < 4; co++)
    z[((n * 16 + cog * 4 + co) * 4 + od) * 1024 + oh * 32 + ow] =
        fminf(fmaxf(acc[co], 0.0f), 6.0f);
}

// VQ (verified)
__global__ __launch_bounds__(256) void vq_k(
    const float* __restrict__ z, const float* __restrict__ emb,
    float* __restrict__ quant, float* __restrict__ codes_out,
    float* __restrict__ stats) {
  __shared__ float se[32 * 16];
  __shared__ float se2[32];
  __shared__ float shist[32];
  __shared__ float swred[4];
  int tid = threadIdx.x;
  for (int i = tid; i < 512; i += 256) {
    int r = i >> 4;
    float v = emb[i];
    if (r == 0) v = 0.0f;
    else if (r == 1) v = 6.0f;
    se[i] = v;
  }
  if (tid < 32) shist[tid] = 0.0f;
  __syncthreads();
  if (tid < 32) {
    float s = 0.0f;
    #pragma unroll
    for (int d = 0; d < 16; d++) { float v = se[tid * 16 + d]; s += v * v; }
    se2[tid] = s;
  }
  __syncthreads();

  int idx = blockIdx.x * 256 + tid;
  float lsum = 0.0f;
  {
    int w_ = idx & 31; int t = idx >> 5;
    int h_ = t & 31; t >>= 5;
    int d_ = t & 3;  int b_ = t >> 2;
    const float* zp = z + b_ * 65536 + d_ * 1024 + h_ * 32 + w_;
    float f[16];
    float f2 = 0.0f;
    #pragma unroll
    for (int c = 0; c < 16; c++) { float v = zp[c * 4096]; f[c] = v; f2 += v * v; }
    float best = 1e30f; int bi = 0;
    for (int e = 0; e < 32; e++) {
      float dot = 0.0f;
      #pragma unroll
      for (int c = 0; c < 16; c++) dot += f[c] * se[e * 16 + c];
      float d2 = f2 - 2.0f * dot + se2[e];
      if (d2 < best) { best = d2; bi = e; }
    }
    float* qp = quant + b_ * 65536 + d_ * 1024 + h_ * 32 + w_;
    #pragma unroll
    for (int c = 0; c < 16; c++) {
      float q = se[bi * 16 + c];
      qp[c * 4096] = q;
      float df = q - f[c];
      lsum += df * df;
    }
    codes_out[idx] = (float)bi;
    atomicAdd(&shist[bi], 1.0f);
  }
  for (int o = 32; o; o >>= 1) lsum += __shfl_down(lsum, o);
  if ((tid & 63) == 0) swred[tid >> 6] = lsum;
  __syncthreads();
  if (tid == 0) atomicAdd(&stats[0], swred[0] + swred[1] + swred[2] + swred[3]);
  if (tid < 32) {
    float h = shist[tid];
    if (h != 0.0f) atomicAdd(&stats[1 + tid], h);
  }
}

__global__ void init_stats_k(float* __restrict__ stats) {
  int tid = threadIdx.x;
  if (tid < 33) stats[tid] = 0.0f;
}

__global__ void fin_k(const float* __restrict__ stats,
                      const float* __restrict__ cluster_size,
                      float* __restrict__ out_loss, float* __restrict__ out_perp,
                      float* __restrict__ out_used) {
  int tid = threadIdx.x;
  float v = 0.0f;
  float used = 0.0f;
  if (tid < 32) {
    float p = stats[1 + tid] * (1.0f / 65536.0f);
    v = p * logf(p + 1e-10f);
    used = (cluster_size[tid] > 1e-5f) ? 1.0f : 0.0f;
  }
  for (int o = 16; o; o >>= 1) { v += __shfl_down(v, o); used += __shfl_down(used, o); }
  if (tid == 0) {
    *out_perp = expf(-v);
    *out_used = used * (1.0f / 32.0f);
    *out_loss = 0.25f * stats[0] * (1.0f / 1048576.0f);
  }
}

// ============ deconv1 strip — templated store target ============
template <int PADDED>
__global__ __launch_bounds__(256) void deconv1_t(
    const float* __restrict__ q, const float* __restrict__ w,
    const float* __restrict__ bias, float* __restrict__ d1) {
  int bid = blockIdx.x;
  int cog = bid & 1;
  int ph  = (bid >> 1) & 1;
  int od  = (bid >> 2) & 7;
  int n   = bid >> 5;
  int tid = threadIdx.x;
  int g   = tid & 7;
  int bl  = tid >> 3;
  bool glf = (g > 0), grf = (g < 7);

  int kd0 = (od + 1) & 1;
  int idtop = (od + 1 - kd0) >> 1;
  int kh0 = (ph + 1) & 1;
  int ihtop = bl + ph;

  float acc[4][8];
  #pragma unroll
  for (int co = 0; co < 4; co++) {
    float bv = bias[cog * 4 + co];
    #pragma unroll
    for (int m = 0; m < 8; m++) acc[co][m] = bv;
  }

  #pragma unroll 1
  for (int ci = 0; ci < 16; ci++) {
    const float* ip = q + ((n * 16 + ci) * 4) * 1024;
    #pragma unroll
    for (int jd = 0; jd < 2; jd++) {
      int id = idtop - jd;
      bool vd = (unsigned)id < 4u;
      int idc = vd ? id : 0;
      const float* plane = ip + idc * 1024;
      #pragma unroll
      for (int jh = 0; jh < 2; jh++) {
        int ih = ihtop - jh;
        bool v = vd && ((unsigned)ih < 32u);
        int ihc = (unsigned)ih < 32u ? ih : 0;
        const float* rp = plane + ihc * 32 + 4 * g;
        float r[6];
        float4 A = ld4(rp);
        float rl = rp[-1 * (int)glf];
        float rr = rp[grf ? 4 : 0];
        r[0] = (v && glf) ? rl : 0.0f;
        r[1] = v ? A.x : 0.0f; r[2] = v ? A.y : 0.0f;
        r[3] = v ? A.z : 0.0f; r[4] = v ? A.w : 0.0f;
        r[5] = (v && grf) ? rr : 0.0f;
        int kd = kd0 + 2 * jd;
        int kh = kh0 + 2 * jh;
        #pragma unroll
        for (int co = 0; co < 4; co++) {
          const float* wb = w + ((ci * 8 + cog * 4 + co) * 4 + kd) * 16 + kh * 4;
          #pragma unroll
          for (int jw = 0; jw < 2; jw++) {
            float w_ev = wb[1 + 2 * jw];
            float w_od = wb[2 * jw];
            #pragma unroll
            for (int ii = 0; ii < 4; ii++) {
              acc[co][2 * ii]     += r[ii + 1 - jw] * w_ev;
              acc[co][2 * ii + 1] += r[ii + 2 - jw] * w_od;
            }
          }
        }
      }
    }
  }
  int oh = 2 * bl + ph;
  #pragma unroll
  for (int co = 0; co < 4; co++) {
    float* op;
    if (PADDED)
      op = d1 + (size_t)(n * 8 + cog * 4 + co) * D1_VOL +
           (od + 1) * D1_PLANE + (oh + 1) * D1_STRIDE + 8 * g + 4;
    else
      op = d1 + ((n * 8 + cog * 4 + co) * 8 + od) * 4096 + oh * 64 + 8 * g;
    float4 lo, hi;
    lo.x = fmaxf(acc[co][0], 0.0f); lo.y = fmaxf(acc[co][1], 0.0f);
    lo.z = fmaxf(acc[co][2], 0.0f); lo.w = fmaxf(acc[co][3], 0.0f);
    hi.x = fmaxf(acc[co][4], 0.0f); hi.y = fmaxf(acc[co][5], 0.0f);
    hi.z = fmaxf(acc[co][6], 0.0f); hi.w = fmaxf(acc[co][7], 0.0f);
    st4(op, lo); st4(op + 4, hi);
  }
}

// ============ deconv3 narrow strip (R9-verified config: tier A uses <1,1>) ============
template <int INP, int OUTP>
__global__ __launch_bounds__(256) void deconv3_t(
    const float* __restrict__ d1, const float* __restrict__ w,
    const float* __restrict__ bias, float* __restrict__ d2) {
  int bid = blockIdx.x;
  int ph  = bid & 1;
  int blh = (bid >> 1) & 3;
  int od  = (bid >> 3) & 15;
  int n   = bid >> 7;
  int tid = threadIdx.x;
  int g   = tid & 15;
  int bl  = tid >> 4;
  int BL  = blh * 16 + bl;
  bool glf = (g > 0), grf = (g < 15);

  int kd0 = (od + 1) & 1;
  int idtop = (od + 1 - kd0) >> 1;
  int kh0 = (ph + 1) & 1;
  int ihtop = BL + ph;

  float acc[4][8];
  #pragma unroll
  for (int co = 0; co < 4; co++) {
    float bv = bias[co];
    #pragma unroll
    for (int m = 0; m < 8; m++) acc[co][m] = bv;
  }

  #pragma unroll 1
  for (int ci = 0; ci < 8; ci++) {
    #pragma unroll
    for (int jd = 0; jd < 2; jd++) {
      #pragma unroll
      for (int jh = 0; jh < 2; jh++) {
        float r[6];
        if (INP) {
          const float* rp = d1 + (size_t)(n * 8 + ci) * D1_VOL +
                            (idtop + 1 - jd) * D1_PLANE + (ihtop + 1 - jh) * D1_STRIDE +
                            4 * g + 4;
          float4 A = ld4(rp);
          r[0] = rp[-1];
          r[1] = A.x; r[2] = A.y; r[3] = A.z; r[4] = A.w;
          r[5] = rp[4];
        } else {
          const float* ip = d1 + ((n * 8 + ci) * 8) * 4096;
          int id = idtop - jd;
          bool vd = (unsigned)id < 8u;
          int idc = vd ? id : 0;
          const float* plane = ip + idc * 4096;
          int ih = ihtop - jh;
          bool v = vd && ((unsigned)ih < 64u);
          int ihc = (unsigned)ih < 64u ? ih : 0;
          const float* rp = plane + ihc * 64 + 4 * g;
          float4 A = ld4(rp);
          float rl = rp[-1 * (int)glf];
          float rr = rp[grf ? 4 : 0];
          r[0] = (v && glf) ? rl : 0.0f;
          r[1] = v ? A.x : 0.0f; r[2] = v ? A.y : 0.0f;
          r[3] = v ? A.z : 0.0f; r[4] = v ? A.w : 0.0f;
          r[5] = (v && grf) ? rr : 0.0f;
        }
        int kd = kd0 + 2 * jd;
        int kh = kh0 + 2 * jh;
        #pragma unroll
        for (int co = 0; co < 4; co++) {
          const float* wb = w + ((ci * 4 + co) * 4 + kd) * 16 + kh * 4;
          #pragma unroll
          for (int jw = 0; jw < 2; jw++) {
            float w_ev = wb[1 + 2 * jw];
            float w_od = wb[2 * jw];
            #pragma unroll
            for (int ii = 0; ii < 4; ii++) {
              acc[co][2 * ii]     += r[ii + 1 - jw] * w_ev;
              acc[co][2 * ii + 1] += r[ii + 2 - jw] * w_od;
            }
          }
        }
      }
    }
  }
  int oh = 2 * BL + ph;
  #pragma unroll
  for (int co = 0; co < 4; co++) {
    float* op;
    if (OUTP)
      op = d2 + (size_t)(n * 4 + co) * P_VOL + (od + 1) * P_PLANE + (oh + 1) * P_STRIDE + 8 * g + 4;
    else
      op = d2 + ((n * 4 + co) * 16 + od) * 16384 + oh * 128 + 8 * g;
    float4 lo, hi;
    lo.x = fmaxf(acc[co][0], 0.0f); lo.y = fmaxf(acc[co][1], 0.0f);
    lo.z = fmaxf(acc[co][2], 0.0f); lo.w = fmaxf(acc[co][3], 0.0f);
    hi.x = fmaxf(acc[co][4], 0.0f); hi.y = fmaxf(acc[co][5], 0.0f);
    hi.z = fmaxf(acc[co][6], 0.0f); hi.w = fmaxf(acc[co][7], 0.0f);
    st4(op, lo); st4(op + 4, hi);
  }
}

// ============ merged halo zeroing (single launch; formulas verbatim from the
// two separately-verified kernels). Part 1: d2p halo (43808*64 elems);
// Part 2: d1p halo (11680*128 elems). Must run after vq_k (d1p overlaps z).
__global__ __launch_bounds__(256) void zero_halos_k(
    float* __restrict__ d2p, float* __restrict__ d1p) {
  const int PER2 = 43808;
  const int T2 = PER2 * 64;        // 2,803,712
  const int PER1 = 11680;
  const int T1 = PER1 * 128;       // 1,495,040
  int total = T2 + T1;
  for (int i = blockIdx.x * 256 + threadIdx.x; i < total; i += gridDim.x * 256) {
    if (i < T2) {
      int nc = i / PER2;
      int j = i - nc * PER2;
      int elem;
      if (j < 35360) {
        int pd = (j < 17680) ? 0 : 17;
        int off = (j < 17680) ? j : j - 17680;
        elem = pd * P_PLANE + off;
      } else if (j < 39712) {
        int k = j - 35360;
        int pd = 1 + (k / 272);
        int rj = k - (pd - 1) * 272;
        int row = (rj < 136) ? 0 : 129;
        int col = (rj < 136) ? rj : rj - 136;
        elem = pd * P_PLANE + row * P_STRIDE + col;
      } else {
        int k = j - 39712;
        int pd = 1 + (k / 256);
        int rj = k - (pd - 1) * 256;
        int row = 1 + (rj >> 1);
        int col = (rj & 1) ? 132 : 3;
        elem = pd * P_PLANE + row * P_STRIDE + col;
      }
      d2p[(size_t)nc * P_VOL + elem] = 0.0f;
    } else {
      int ii = i - T2;
      int nc = ii / PER1;
      int j = ii - nc * PER1;
      int elem;
      if (j < 9504) {
        int pd = (j < 4752) ? 0 : 9;
        int off = (j < 4752) ? j : j - 4752;
        elem = pd * D1_PLANE + off;
      } else if (j < 10656) {
        int k = j - 9504;
        int pd = 1 + (k / 144);
        int rj = k - (pd - 1) * 144;
        int row = (rj < 72) ? 0 : 65;
        int col = (rj < 72) ? rj : rj - 72;
        elem = pd * D1_PLANE + row * D1_STRIDE + col;
      } else {
        int k = j - 10656;
        int pd = 1 + (k / 128);
        int rj = k - (pd - 1) * 128;
        int row = 1 + (rj >> 1);
        int col = (rj & 1) ? 68 : 3;
        elem = pd * D1_PLANE + row * D1_STRIDE + col;
      }
      d1p[(size_t)nc * D1_VOL + elem] = 0.0f;
    }
  }
}

// zero the read-but-never-written halo of d2p (tier B only)
__global__ __launch_bounds__(256) void zero_halo_k(float* __restrict__ d2p) {
  const int PER = 43808;
  int total = PER * 64;
  for (int i = blockIdx.x * 256 + threadIdx.x; i < total; i += gridDim.x * 256) {
    int nc = i / PER;
    int j = i - nc * PER;
    int elem;
    if (j < 35360) {
      int pd = (j < 17680) ? 0 : 17;
      int off = (j < 17680) ? j : j - 17680;
      elem = pd * P_PLANE + off;
    } else if (j < 39712) {
      int k = j - 35360;
      int pd = 1 + (k / 272);
      int rj = k - (pd - 1) * 272;
      int row = (rj < 136) ? 0 : 129;
      int col = (rj < 136) ? rj : rj - 136;
      elem = pd * P_PLANE + row * P_STRIDE + col;
    } else {
      int k = j - 39712;
      int pd = 1 + (k / 256);
      int rj = k - (pd - 1) * 256;
      int row = 1 + (rj >> 1);
      int col = (rj & 1) ? 132 : 3;
      elem = pd * P_PLANE + row * P_STRIDE + col;
    }
    d2p[(size_t)nc * P_VOL + elem] = 0.0f;
  }
}

// ============ deconv4 cube, legacy (verified 78.6us, tier-C fallback) ============
__global__ __launch_bounds__(256) void deconv4_k(
    const float* __restrict__ d2, const float* __restrict__ w,
    const float* __restrict__ bias, float* __restrict__ out) {
  int idx = blockIdx.x * 256 + threadIdx.x;
  int c = idx & 63;
  int b = (idx >> 6) & 63;
  int a = (idx >> 12) & 7;
  int n = idx >> 15;
  float acc[2][2][2][3];
  #pragma unroll
  for (int pd = 0; pd < 2; pd++)
    #pragma unroll
    for (int ph = 0; ph < 2; ph++)
      #pragma unroll
      for (int pw = 0; pw < 2; pw++)
        #pragma unroll
        for (int co = 0; co < 3; co++) acc[pd][ph][pw][co] = bias[co];
  int ih0 = 2 * b - 1, iw0 = 2 * c - 1;
  bool vh[4], vw[4];
  #pragma unroll
  for (int l = 0; l < 4; l++) {
    vh[l] = (unsigned)(ih0 + l) < 128u;
    vw[l] = (unsigned)(iw0 + l) < 128u;
  }
  #pragma unroll 1
  for (int ci = 0; ci < 4; ci++) {
    const float* ip = d2 + ((n * 4 + ci) * 16) * 16384;
    #pragma unroll
    for (int ld = 0; ld < 4; ld++) {
      int id = 2 * a - 1 + ld;
      bool vdl = (unsigned)id < 16u;
      const float* pp = ip + id * 16384;
      float p[4][4];
      #pragma unroll
      for (int lh = 0; lh < 4; lh++)
        #pragma unroll
        for (int lw = 0; lw < 4; lw++)
          p[lh][lw] = (vdl && vh[lh] && vw[lw]) ? pp[(ih0 + lh) * 128 + (iw0 + lw)] : 0.0f;
      #pragma unroll
      for (int pd = 0; pd < 2; pd++) {
        int kd = pd + 2 - ld;
        if (kd < 0 || kd > 2) continue;
        #pragma unroll
        for (int kh = 0; kh < 3; kh++)
          #pragma unroll
          for (int kw = 0; kw < 3; kw++)
            #pragma unroll
            for (int co = 0; co < 3; co++) {
              float wv = w[(ci * 3 + co) * 27 + kd * 9 + kh * 3 + kw];
              #pragma unroll
              for (int ph = 0; ph < 2; ph++)
                #pragma unroll
                for (int pw = 0; pw < 2; pw++)
                  acc[pd][ph][pw][co] += p[ph + 2 - kh][pw + 2 - kw] * wv;
            }
      }
    }
  }
  #pragma unroll
  for (int co = 0; co < 3; co++)
    #pragma unroll
    for (int pd = 0; pd < 2; pd++)
      #pragma unroll
      for (int ph = 0; ph < 2; ph++)
        #pragma unroll
        for (int pw = 0; pw < 2; pw++)
          out[((n * 3 + co) * 16 + 2 * a + pd) * 16384 +
              (2 * b + ph) * 128 + (2 * c + pw)] = acc[pd][ph][pw][co];
}

// ============ deconv4 wide cube, padded input (R9/R11 verified 49.8us) ============
// Thread = 2(d) x 2(h) x 4(w) x 3 co; 3 fully-coalesced ld4 per row.
__global__ __launch_bounds__(256) void deconv4p_k(
    const float* __restrict__ d2p, const float* __restrict__ w,
    const float* __restrict__ bias, float* __restrict__ out) {
  int idx = blockIdx.x * 256 + threadIdx.x;
  int c = idx & 31;          // ow base 4c
  int b = (idx >> 5) & 63;   // oh base 2b
  int a = (idx >> 11) & 7;   // od base 2a
  int n = idx >> 14;
  float acc[2][2][3][4];     // [pd][ph][co][pw]
  #pragma unroll
  for (int pd = 0; pd < 2; pd++)
    #pragma unroll
    for (int ph = 0; ph < 2; ph++)
      #pragma unroll
      for (int co = 0; co < 3; co++) {
        float bv = bias[co];
        #pragma unroll
        for (int pw = 0; pw < 4; pw++) acc[pd][ph][co][pw] = bv;
      }
  #pragma unroll 1
  for (int ci = 0; ci < 4; ci++) {
    const float* ip = d2p + (size_t)(n * 4 + ci) * P_VOL +
                      (2 * a) * P_PLANE + (2 * b) * P_STRIDE + (4 * c);
    #pragma unroll
    for (int ld = 0; ld < 4; ld++) {
      const float* pp = ip + ld * P_PLANE;
      float pr[4][12];
      #pragma unroll
      for (int lh = 0; lh < 4; lh++) {
        const float* rp = pp + lh * P_STRIDE;
        float4 A = ld4(rp);
        float4 B = ld4(rp + 4);
        float4 C = ld4(rp + 8);
        pr[lh][0] = A.x;  pr[lh][1] = A.y;  pr[lh][2] = A.z;  pr[lh][3] = A.w;
        pr[lh][4] = B.x;  pr[lh][5] = B.y;  pr[lh][6] = B.z;  pr[lh][7] = B.w;
        pr[lh][8] = C.x;  pr[lh][9] = C.y;  pr[lh][10] = C.z; pr[lh][11] = C.w;
      }
      #pragma unroll
      for (int pd = 0; pd < 2; pd++) {
        int kd = pd + 2 - ld;
        if (kd < 0 || kd > 2) continue;
        #pragma unroll
        for (int kh = 0; kh < 3; kh++)
          #pragma unroll
          for (int kw = 0; kw < 3; kw++)
            #pragma unroll
            for (int co = 0; co < 3; co++) {
              float wv = w[(ci * 3 + co) * 27 + kd * 9 + kh * 3 + kw];
              #pragma unroll
              for (int ph = 0; ph < 2; ph++)
                #pragma unroll
                for (int pw = 0; pw < 4; pw++)
                  acc[pd][ph][co][pw] += pr[ph + 2 - kh][pw + 5 - kw] * wv;
            }
      }
    }
  }
  #pragma unroll
  for (int co = 0; co < 3; co++)
    #pragma unroll
    for (int pd = 0; pd < 2; pd++)
      #pragma unroll
      for (int ph = 0; ph < 2; ph++) {
        float4 o;
        o.x = acc[pd][ph][co][0]; o.y = acc[pd][ph][co][1];
        o.z = acc[pd][ph][co][2]; o.w = acc[pd][ph][co][3];
        st4(out + ((n * 3 + co) * 16 + 2 * a + pd) * 16384 +
            (2 * b + ph) * 128 + 4 * c, o);
      }
}

extern "C" void kernel_launch(void* const* d_in, const int* in_sizes, int n_in,
                              void* d_out, int out_size, void* d_ws, size_t ws_size,
                              hipStream_t stream) {
  const float* x      = (const float*)d_in[0];
  const float* enc_w1 = (const float*)d_in[2];
  const float* enc_b1 = (const float*)d_in[3];
  const float* enc_w2 = (const float*)d_in[4];
  const float* enc_b2 = (const float*)d_in[5];
  const float* enc_w4 = (const float*)d_in[6];
  const float* enc_b4 = (const float*)d_in[7];
  const float* dec_w1 = (const float*)d_in[8];
  const float* dec_b1 = (const float*)d_in[9];
  const float* dec_w3 = (const float*)d_in[10];
  const float* dec_b3 = (const float*)d_in[11];
  const float* dec_w4 = (const float*)d_in[12];
  const float* dec_b4 = (const float*)d_in[13];
  const float* emb    = (const float*)d_in[14];
  const float* csize  = (const float*)d_in[15];

  float* ws = (float*)d_ws;
  float* stats = ws;                      // 64
  float* quant = ws + 64;                 // 1,048,576
  float* z     = quant + 1048576;         // 1,048,576
  float* y2    = z + 1048576;             // 524,288
  float* y1    = y2 + 524288;             // 2,097,152 (dead after conv2)

  float* out   = (float*)d_out;                        // 12,582,912
  float* out_loss  = out + 12582912;
  float* out_codes = out_loss + 1;                     // 65,536
  float* out_perp  = out_codes + 65536;
  float* out_used  = out_perp + 1;

  // Tier A (full pad): d1p (6,082,560) + d2p (20,367,360)
  const size_t FULL_NEED = (size_t)(64 + 1048576 + 6082560 + 20367360) * sizeof(float);
  // Tier B: legacy d1 (4,194,304) + d2p
  const size_t MID_NEED  = (size_t)(64 + 1048576 + 4194304 + 20367360) * sizeof(float);

  init_stats_k<<<1, 64, 0, stream>>>(stats);

  conv1_k<<<512, 256, 0, stream>>>(x, enc_w1, enc_b1, y1);
  conv2_k<<<512, 256, 0, stream>>>(y1, enc_w2, enc_b2, y2);
  conv4_k<<<1024, 256, 0, stream>>>(y2, enc_w4, enc_b4, z);

  vq_k<<<256, 256, 0, stream>>>(z, emb, quant, out_codes, stats);
  fin_k<<<1, 64, 0, stream>>>(stats, csize, out_loss, out_perp, out_used);

  if (ws_size >= FULL_NEED) {
    float* d1p = ws + 64 + 1048576;                  // overlaps dead z/y2/y1
    float* d2p = d1p + 6082560;
    zero_halos_k<<<2048, 256, 0, stream>>>(d2p, d1p);  // after vq_k: z now dead
    deconv1_t<1><<<512, 256, 0, stream>>>(quant, dec_w1, dec_b1, d1p);
    deconv3_t<1, 1><<<2048, 256, 0, stream>>>(d1p, dec_w3, dec_b3, d2p);
    deconv4p_k<<<1024, 256, 0, stream>>>(d2p, dec_w4, dec_b4, out);
  } else if (ws_size >= MID_NEED) {
    float* d1  = ws + 64 + 1048576;
    float* d2p = d1 + 4194304;
    zero_halo_k<<<1024, 256, 0, stream>>>(d2p);
    deconv1_t<0><<<512, 256, 0, stream>>>(quant, dec_w1, dec_b1, d1);
    deconv3_t<0, 1><<<2048, 256, 0, stream>>>(d1, dec_w3, dec_b3, d2p);
    deconv4p_k<<<1024, 256, 0, stream>>>(d2p, dec_w4, dec_b4, out);
  } else {
    float* d1 = ws + 64 + 1048576;
    float* d2 = d1 + 4194304;
    deconv1_t<0><<<512, 256, 0, stream>>>(quant, dec_w1, dec_b1, d1);
    deconv3_t<0, 0><<<2048, 256, 0, stream>>>(d1, dec_w3, dec_b3, d2);
    deconv4_k<<<2048, 256, 0, stream>>>(d2, dec_w4, dec_b4, out);
  }
}

// Round 13
// 345.297 us; speedup vs baseline: 1.0360x; 1.0131x over previous
//
#include <hip/hip_runtime.h>
#include <math.h>

#define NB 16

// ---------------- shapes ----------------
// x:      (16, 3,16,128,128)
// y1:     (16, 4, 8, 64, 64)   conv1 k4 s2 p1 + relu
// y2:     (16, 8, 4, 32, 32)   conv2 k4 s2 p1 + relu
// z:      (16,16, 4, 32, 32)   conv4 k3 s1 p1 + clip(0,6)
// quant:  (16,16, 4, 32, 32)   VQ
// d1:     (16, 8, 8, 64, 64)   deconv1 k4 s2 p1 + relu  (padded: [10][66][72])
// d2:     (16, 4,16,128,128)   deconv3 k4 s2 p1 + relu  (padded: [18][130][136])
// out:    (16, 3,16,128,128)   deconv4 k3 s1 p1

// padded d2 geometry
#define P_STRIDE 136              // col = iw + 4; 16B-aligned rows
#define P_PLANE  (130 * P_STRIDE) // row = ih + 1
#define P_VOL    (18 * P_PLANE)   // plane = id + 1
// padded d1 geometry
#define D1_STRIDE 72              // col = iw + 4
#define D1_PLANE  (66 * D1_STRIDE)
#define D1_VOL    (10 * D1_PLANE)

__device__ __forceinline__ float4 ld4(const float* p) {
  return *reinterpret_cast<const float4*>(p);
}
__device__ __forceinline__ void st4(float* p, float4 v) {
  *reinterpret_cast<float4*>(p) = v;
}

// conv1 (R4 strip, measured fast): thread = 4 co x (1 od, 1 oh, 4 ow). 512 blocks.
__global__ __launch_bounds__(256) void conv1_k(
    const float* __restrict__ x, const float* __restrict__ w,
    const float* __restrict__ bias, float* __restrict__ y) {
  int idx = blockIdx.x * 256 + threadIdx.x;
  int g  = idx & 15;
  int oh = (idx >> 4) & 63;
  int od = (idx >> 10) & 7;
  int n  = idx >> 13;
  bool gl = (g > 0), gr = (g < 15);
  float acc[4][4];
  #pragma unroll
  for (int co = 0; co < 4; co++) {
    float bv = bias[co];
    #pragma unroll
    for (int m = 0; m < 4; m++) acc[co][m] = bv;
  }
  int ih0 = 2 * oh - 1;
  #pragma unroll 1
  for (int ci = 0; ci < 3; ci++) {
    #pragma unroll 1
    for (int kd = 0; kd < 4; kd++) {
      int id = 2 * od - 1 + kd;
      bool vd = (unsigned)id < 16u;
      int idc = vd ? id : 0;
      const float* plane = x + (((n * 3 + ci) * 16 + idc) * 16384);
      #pragma unroll
      for (int kh = 0; kh < 4; kh++) {
        int ih = ih0 + kh;
        bool v = vd && ((unsigned)ih < 128u);
        int ihc = (unsigned)ih < 128u ? ih : 0;
        const float* rp = plane + ihc * 128 + 8 * g;
        float r[10];
        float4 A = ld4(rp);
        float4 B = ld4(rp + 4);
        float rl = rp[-1 * (int)gl];
        float rr = rp[gr ? 8 : 0];
        r[0] = (v && gl) ? rl : 0.0f;
        r[1] = v ? A.x : 0.0f; r[2] = v ? A.y : 0.0f;
        r[3] = v ? A.z : 0.0f; r[4] = v ? A.w : 0.0f;
        r[5] = v ? B.x : 0.0f; r[6] = v ? B.y : 0.0f;
        r[7] = v ? B.z : 0.0f; r[8] = v ? B.w : 0.0f;
        r[9] = (v && gr) ? rr : 0.0f;
        #pragma unroll
        for (int co = 0; co < 4; co++) {
          const float* wb = w + ((co * 3 + ci) * 4 + kd) * 16 + kh * 4;
          #pragma unroll
          for (int kw = 0; kw < 4; kw++) {
            float wv = wb[kw];
            #pragma unroll
            for (int m = 0; m < 4; m++)
              acc[co][m] += r[2 * m + kw] * wv;
          }
        }
      }
    }
  }
  #pragma unroll
  for (int co = 0; co < 4; co++) {
    float4 o;
    o.x = fmaxf(acc[co][0], 0.0f); o.y = fmaxf(acc[co][1], 0.0f);
    o.z = fmaxf(acc[co][2], 0.0f); o.w = fmaxf(acc[co][3], 0.0f);
    st4(y + ((n * 4 + co) * 8 + od) * 4096 + oh * 64 + 4 * g, o);
  }
}

// conv2: thread = 1 pos x 4 co. 512 blocks.
__global__ __launch_bounds__(256) void conv2_k(
    const float* __restrict__ y1, const float* __restrict__ w,
    const float* __restrict__ bias, float* __restrict__ y) {
  int idx = blockIdx.x * 256 + threadIdx.x;
  int ow = idx & 31;
  int oh = (idx >> 5) & 31;
  int od = (idx >> 10) & 3;
  int n = (idx >> 12) & 15;
  int cog = idx >> 16;
  float acc[4];
  #pragma unroll
  for (int co = 0; co < 4; co++) acc[co] = bias[cog * 4 + co];
  int id0 = 2 * od - 1, ih0 = 2 * oh - 1, iw0 = 2 * ow - 1;
  bool vh[4], vw[4];
  #pragma unroll
  for (int l = 0; l < 4; l++) {
    vh[l] = (unsigned)(ih0 + l) < 64u;
    vw[l] = (unsigned)(iw0 + l) < 64u;
  }
  #pragma unroll 1
  for (int ci = 0; ci < 4; ci++) {
    const float* ip = y1 + ((n * 4 + ci) * 8) * 4096;
    #pragma unroll
    for (int kd = 0; kd < 4; kd++) {
      int id = id0 + kd;
      bool vd = (unsigned)id < 8u;
      const float* pp = ip + id * 4096;
      float p[4][4];
      #pragma unroll
      for (int kh = 0; kh < 4; kh++)
        #pragma unroll
        for (int kw = 0; kw < 4; kw++)
          p[kh][kw] = (vd && vh[kh] && vw[kw]) ? pp[(ih0 + kh) * 64 + (iw0 + kw)] : 0.0f;
      #pragma unroll
      for (int co = 0; co < 4; co++) {
        const float* wp = w + (((cog * 4 + co) * 4 + ci) * 4 + kd) * 16;
        #pragma unroll
        for (int kh = 0; kh < 4; kh++)
          #pragma unroll
          for (int kw = 0; kw < 4; kw++)
            acc[co] += p[kh][kw] * wp[kh * 4 + kw];
      }
    }
  }
  #pragma unroll
  for (int co = 0; co < 4; co++)
    y[((n * 8 + cog * 4 + co) * 4 + od) * 1024 + oh * 32 + ow] = fmaxf(acc[co], 0.0f);
}

// conv4: thread = 1 pos x 4 co. 1024 blocks.
__global__ __launch_bounds__(256) void conv4_k(
    const float* __restrict__ y2, const float* __restrict__ w,
    const float* __restrict__ bias, float* __restrict__ z) {
  int idx = blockIdx.x * 256 + threadIdx.x;
  int ow = idx & 31;
  int oh = (idx >> 5) & 31;
  int od = (idx >> 10) & 3;
  int n = (idx >> 12) & 15;
  int cog = idx >> 16;
  float acc[4];
  #pragma unroll
  for (int co = 0; co < 4; co++) acc[co] = bias[cog * 4 + co];
  bool vh[3], vw[3];
  #pragma unroll
  for (int l = 0; l < 3; l++) {
    vh[l] = (unsigned)(oh - 1 + l) < 32u;
    vw[l] = (unsigned)(ow - 1 + l) < 32u;
  }
  #pragma unroll 1
  for (int ci = 0; ci < 8; ci++) {
    const float* ip = y2 + ((n * 8 + ci) * 4) * 1024;
    #pragma unroll
    for (int kd = 0; kd < 3; kd++) {
      int id = od - 1 + kd;
      bool vd = (unsigned)id < 4u;
      const float* pp = ip + id * 1024;
      float p[3][3];
      #pragma unroll
      for (int kh = 0; kh < 3; kh++)
        #pragma unroll
        for (int kw = 0; kw < 3; kw++)
          p[kh][kw] = (vd && vh[kh] && vw[kw]) ? pp[(oh - 1 + kh) * 32 + (ow - 1 + kw)] : 0.0f;
      #pragma unroll
      for (int co = 0; co < 4; co++) {
        const float* wp = w + (((cog * 4 + co) * 8 + ci) * 3 + kd) * 9;
        #pragma unroll
        for (int kh = 0; kh < 3; kh++)
          #pragma unroll
          for (int kw = 0; kw < 3; kw++)
            acc[co] += p[kh][kw] * wp[kh * 3 + kw];
      }
    }
  }
  #pragma unroll
  for (int co = 0; co < 4; co++)
    z[((n * 16 + cog * 4 + co) * 4 + od) * 1024 + oh * 32 + ow] =
        fminf(fmaxf(acc[co], 0.0f), 6.0f);
}

// VQ (verified)
__global__ __launch_bounds__(256) void vq_k(
    const float* __restrict__ z, const float* __restrict__ emb,
    float* __restrict__ quant, float* __restrict__ codes_out,
    float* __restrict__ stats) {
  __shared__ float se[32 * 16];
  __shared__ float se2[32];
  __shared__ float shist[32];
  __shared__ float swred[4];
  int tid = threadIdx.x;
  for (int i = tid; i < 512; i += 256) {
    int r = i >> 4;
    float v = emb[i];
    if (r == 0) v = 0.0f;
    else if (r == 1) v = 6.0f;
    se[i] = v;
  }
  if (tid < 32) shist[tid] = 0.0f;
  __syncthreads();
  if (tid < 32) {
    float s = 0.0f;
    #pragma unroll
    for (int d = 0; d < 16; d++) { float v = se[tid * 16 + d]; s += v * v; }
    se2[tid] = s;
  }
  __syncthreads();

  int idx = blockIdx.x * 256 + tid;
  float lsum = 0.0f;
  {
    int w_ = idx & 31; int t = idx >> 5;
    int h_ = t & 31; t >>= 5;
    int d_ = t & 3;  int b_ = t >> 2;
    const float* zp = z + b_ * 65536 + d_ * 1024 + h_ * 32 + w_;
    float f[16];
    float f2 = 0.0f;
    #pragma unroll
    for (int c = 0; c < 16; c++) { float v = zp[c * 4096]; f[c] = v; f2 += v * v; }
    float best = 1e30f; int bi = 0;
    for (int e = 0; e < 32; e++) {
      float dot = 0.0f;
      #pragma unroll
      for (int c = 0; c < 16; c++) dot += f[c] * se[e * 16 + c];
      float d2 = f2 - 2.0f * dot + se2[e];
      if (d2 < best) { best = d2; bi = e; }
    }
    float* qp = quant + b_ * 65536 + d_ * 1024 + h_ * 32 + w_;
    #pragma unroll
    for (int c = 0; c < 16; c++) {
      float q = se[bi * 16 + c];
      qp[c * 4096] = q;
      float df = q - f[c];
      lsum += df * df;
    }
    codes_out[idx] = (float)bi;
    atomicAdd(&shist[bi], 1.0f);
  }
  for (int o = 32; o; o >>= 1) lsum += __shfl_down(lsum, o);
  if ((tid & 63) == 0) swred[tid >> 6] = lsum;
  __syncthreads();
  if (tid == 0) atomicAdd(&stats[0], swred[0] + swred[1] + swred[2] + swred[3]);
  if (tid < 32) {
    float h = shist[tid];
    if (h != 0.0f) atomicAdd(&stats[1 + tid], h);
  }
}

__global__ void init_stats_k(float* __restrict__ stats) {
  int tid = threadIdx.x;
  if (tid < 33) stats[tid] = 0.0f;
}

__global__ void fin_k(const float* __restrict__ stats,
                      const float* __restrict__ cluster_size,
                      float* __restrict__ out_loss, float* __restrict__ out_perp,
                      float* __restrict__ out_used) {
  int tid = threadIdx.x;
  float v = 0.0f;
  float used = 0.0f;
  if (tid < 32) {
    float p = stats[1 + tid] * (1.0f / 65536.0f);
    v = p * logf(p + 1e-10f);
    used = (cluster_size[tid] > 1e-5f) ? 1.0f : 0.0f;
  }
  for (int o = 16; o; o >>= 1) { v += __shfl_down(v, o); used += __shfl_down(used, o); }
  if (tid == 0) {
    *out_perp = expf(-v);
    *out_used = used * (1.0f / 32.0f);
    *out_loss = 0.25f * stats[0] * (1.0f / 1048576.0f);
  }
}

// ============ deconv1 strip — templated store target ============
template <int PADDED>
__global__ __launch_bounds__(256) void deconv1_t(
    const float* __restrict__ q, const float* __restrict__ w,
    const float* __restrict__ bias, float* __restrict__ d1) {
  int bid = blockIdx.x;
  int cog = bid & 1;
  int ph  = (bid >> 1) & 1;
  int od  = (bid >> 2) & 7;
  int n   = bid >> 5;
  int tid = threadIdx.x;
  int g   = tid & 7;
  int bl  = tid >> 3;
  bool glf = (g > 0), grf = (g < 7);

  int kd0 = (od + 1) & 1;
  int idtop = (od + 1 - kd0) >> 1;
  int kh0 = (ph + 1) & 1;
  int ihtop = bl + ph;

  float acc[4][8];
  #pragma unroll
  for (int co = 0; co < 4; co++) {
    float bv = bias[cog * 4 + co];
    #pragma unroll
    for (int m = 0; m < 8; m++) acc[co][m] = bv;
  }

  #pragma unroll 1
  for (int ci = 0; ci < 16; ci++) {
    const float* ip = q + ((n * 16 + ci) * 4) * 1024;
    #pragma unroll
    for (int jd = 0; jd < 2; jd++) {
      int id = idtop - jd;
      bool vd = (unsigned)id < 4u;
      int idc = vd ? id : 0;
      const float* plane = ip + idc * 1024;
      #pragma unroll
      for (int jh = 0; jh < 2; jh++) {
        int ih = ihtop - jh;
        bool v = vd && ((unsigned)ih < 32u);
        int ihc = (unsigned)ih < 32u ? ih : 0;
        const float* rp = plane + ihc * 32 + 4 * g;
        float r[6];
        float4 A = ld4(rp);
        float rl = rp[-1 * (int)glf];
        float rr = rp[grf ? 4 : 0];
        r[0] = (v && glf) ? rl : 0.0f;
        r[1] = v ? A.x : 0.0f; r[2] = v ? A.y : 0.0f;
        r[3] = v ? A.z : 0.0f; r[4] = v ? A.w : 0.0f;
        r[5] = (v && grf) ? rr : 0.0f;
        int kd = kd0 + 2 * jd;
        int kh = kh0 + 2 * jh;
        #pragma unroll
        for (int co = 0; co < 4; co++) {
          const float* wb = w + ((ci * 8 + cog * 4 + co) * 4 + kd) * 16 + kh * 4;
          #pragma unroll
          for (int jw = 0; jw < 2; jw++) {
            float w_ev = wb[1 + 2 * jw];
            float w_od = wb[2 * jw];
            #pragma unroll
            for (int ii = 0; ii < 4; ii++) {
              acc[co][2 * ii]     += r[ii + 1 - jw] * w_ev;
              acc[co][2 * ii + 1] += r[ii + 2 - jw] * w_od;
            }
          }
        }
      }
    }
  }
  int oh = 2 * bl + ph;
  #pragma unroll
  for (int co = 0; co < 4; co++) {
    float* op;
    if (PADDED)
      op = d1 + (size_t)(n * 8 + cog * 4 + co) * D1_VOL +
           (od + 1) * D1_PLANE + (oh + 1) * D1_STRIDE + 8 * g + 4;
    else
      op = d1 + ((n * 8 + cog * 4 + co) * 8 + od) * 4096 + oh * 64 + 8 * g;
    float4 lo, hi;
    lo.x = fmaxf(acc[co][0], 0.0f); lo.y = fmaxf(acc[co][1], 0.0f);
    lo.z = fmaxf(acc[co][2], 0.0f); lo.w = fmaxf(acc[co][3], 0.0f);
    hi.x = fmaxf(acc[co][4], 0.0f); hi.y = fmaxf(acc[co][5], 0.0f);
    hi.z = fmaxf(acc[co][6], 0.0f); hi.w = fmaxf(acc[co][7], 0.0f);
    st4(op, lo); st4(op + 4, hi);
  }
}

// ============ deconv3 narrow strip; INP=1 path now uses 3 full ld4 per row
// (R10/R11 lesson: full-width coalesced issues beat quarter-width scalars) ====
template <int INP, int OUTP>
__global__ __launch_bounds__(256) void deconv3_t(
    const float* __restrict__ d1, const float* __restrict__ w,
    const float* __restrict__ bias, float* __restrict__ d2) {
  int bid = blockIdx.x;
  int ph  = bid & 1;
  int blh = (bid >> 1) & 3;
  int od  = (bid >> 3) & 15;
  int n   = bid >> 7;
  int tid = threadIdx.x;
  int g   = tid & 15;
  int bl  = tid >> 4;
  int BL  = blh * 16 + bl;
  bool glf = (g > 0), grf = (g < 15);

  int kd0 = (od + 1) & 1;
  int idtop = (od + 1 - kd0) >> 1;
  int kh0 = (ph + 1) & 1;
  int ihtop = BL + ph;

  float acc[4][8];
  #pragma unroll
  for (int co = 0; co < 4; co++) {
    float bv = bias[co];
    #pragma unroll
    for (int m = 0; m < 8; m++) acc[co][m] = bv;
  }

  #pragma unroll 1
  for (int ci = 0; ci < 8; ci++) {
    #pragma unroll
    for (int jd = 0; jd < 2; jd++) {
      #pragma unroll
      for (int jh = 0; jh < 2; jh++) {
        float r[6];
        if (INP) {
          // window cols 4g+3 .. 4g+8 of padded row; load as 3 aligned ld4
          // (cols 4g..4g+11, all within [0,72)) — full-width coalesced issues.
          const float* rp = d1 + (size_t)(n * 8 + ci) * D1_VOL +
                            (idtop + 1 - jd) * D1_PLANE + (ihtop + 1 - jh) * D1_STRIDE +
                            4 * g + 4;
          float4 A0 = ld4(rp - 4);
          float4 A  = ld4(rp);
          float4 B0 = ld4(rp + 4);
          r[0] = A0.w;
          r[1] = A.x; r[2] = A.y; r[3] = A.z; r[4] = A.w;
          r[5] = B0.x;
        } else {
          const float* ip = d1 + ((n * 8 + ci) * 8) * 4096;
          int id = idtop - jd;
          bool vd = (unsigned)id < 8u;
          int idc = vd ? id : 0;
          const float* plane = ip + idc * 4096;
          int ih = ihtop - jh;
          bool v = vd && ((unsigned)ih < 64u);
          int ihc = (unsigned)ih < 64u ? ih : 0;
          const float* rp = plane + ihc * 64 + 4 * g;
          float4 A = ld4(rp);
          float rl = rp[-1 * (int)glf];
          float rr = rp[grf ? 4 : 0];
          r[0] = (v && glf) ? rl : 0.0f;
          r[1] = v ? A.x : 0.0f; r[2] = v ? A.y : 0.0f;
          r[3] = v ? A.z : 0.0f; r[4] = v ? A.w : 0.0f;
          r[5] = (v && grf) ? rr : 0.0f;
        }
        int kd = kd0 + 2 * jd;
        int kh = kh0 + 2 * jh;
        #pragma unroll
        for (int co = 0; co < 4; co++) {
          const float* wb = w + ((ci * 4 + co) * 4 + kd) * 16 + kh * 4;
          #pragma unroll
          for (int jw = 0; jw < 2; jw++) {
            float w_ev = wb[1 + 2 * jw];
            float w_od = wb[2 * jw];
            #pragma unroll
            for (int ii = 0; ii < 4; ii++) {
              acc[co][2 * ii]     += r[ii + 1 - jw] * w_ev;
              acc[co][2 * ii + 1] += r[ii + 2 - jw] * w_od;
            }
          }
        }
      }
    }
  }
  int oh = 2 * BL + ph;
  #pragma unroll
  for (int co = 0; co < 4; co++) {
    float* op;
    if (OUTP)
      op = d2 + (size_t)(n * 4 + co) * P_VOL + (od + 1) * P_PLANE + (oh + 1) * P_STRIDE + 8 * g + 4;
    else
      op = d2 + ((n * 4 + co) * 16 + od) * 16384 + oh * 128 + 8 * g;
    float4 lo, hi;
    lo.x = fmaxf(acc[co][0], 0.0f); lo.y = fmaxf(acc[co][1], 0.0f);
    lo.z = fmaxf(acc[co][2], 0.0f); lo.w = fmaxf(acc[co][3], 0.0f);
    hi.x = fmaxf(acc[co][4], 0.0f); hi.y = fmaxf(acc[co][5], 0.0f);
    hi.z = fmaxf(acc[co][6], 0.0f); hi.w = fmaxf(acc[co][7], 0.0f);
    st4(op, lo); st4(op + 4, hi);
  }
}

// ============ merged halo zeroing (single launch, verified R12) ============
__global__ __launch_bounds__(256) void zero_halos_k(
    float* __restrict__ d2p, float* __restrict__ d1p) {
  const int PER2 = 43808;
  const int T2 = PER2 * 64;
  const int PER1 = 11680;
  const int T1 = PER1 * 128;
  int total = T2 + T1;
  for (int i = blockIdx.x * 256 + threadIdx.x; i < total; i += gridDim.x * 256) {
    if (i < T2) {
      int nc = i / PER2;
      int j = i - nc * PER2;
      int elem;
      if (j < 35360) {
        int pd = (j < 17680) ? 0 : 17;
        int off = (j < 17680) ? j : j - 17680;
        elem = pd * P_PLANE + off;
      } else if (j < 39712) {
        int k = j - 35360;
        int pd = 1 + (k / 272);
        int rj = k - (pd - 1) * 272;
        int row = (rj < 136) ? 0 : 129;
        int col = (rj < 136) ? rj : rj - 136;
        elem = pd * P_PLANE + row * P_STRIDE + col;
      } else {
        int k = j - 39712;
        int pd = 1 + (k / 256);
        int rj = k - (pd - 1) * 256;
        int row = 1 + (rj >> 1);
        int col = (rj & 1) ? 132 : 3;
        elem = pd * P_PLANE + row * P_STRIDE + col;
      }
      d2p[(size_t)nc * P_VOL + elem] = 0.0f;
    } else {
      int ii = i - T2;
      int nc = ii / PER1;
      int j = ii - nc * PER1;
      int elem;
      if (j < 9504) {
        int pd = (j < 4752) ? 0 : 9;
        int off = (j < 4752) ? j : j - 4752;
        elem = pd * D1_PLANE + off;
      } else if (j < 10656) {
        int k = j - 9504;
        int pd = 1 + (k / 144);
        int rj = k - (pd - 1) * 144;
        int row = (rj < 72) ? 0 : 65;
        int col = (rj < 72) ? rj : rj - 72;
        elem = pd * D1_PLANE + row * D1_STRIDE + col;
      } else {
        int k = j - 10656;
        int pd = 1 + (k / 128);
        int rj = k - (pd - 1) * 128;
        int row = 1 + (rj >> 1);
        int col = (rj & 1) ? 68 : 3;
        elem = pd * D1_PLANE + row * D1_STRIDE + col;
      }
      d1p[(size_t)nc * D1_VOL + elem] = 0.0f;
    }
  }
}

// zero the read-but-never-written halo of d2p (tier B only)
__global__ __launch_bounds__(256) void zero_halo_k(float* __restrict__ d2p) {
  const int PER = 43808;
  int total = PER * 64;
  for (int i = blockIdx.x * 256 + threadIdx.x; i < total; i += gridDim.x * 256) {
    int nc = i / PER;
    int j = i - nc * PER;
    int elem;
    if (j < 35360) {
      int pd = (j < 17680) ? 0 : 17;
      int off = (j < 17680) ? j : j - 17680;
      elem = pd * P_PLANE + off;
    } else if (j < 39712) {
      int k = j - 35360;
      int pd = 1 + (k / 272);
      int rj = k - (pd - 1) * 272;
      int row = (rj < 136) ? 0 : 129;
      int col = (rj < 136) ? rj : rj - 136;
      elem = pd * P_PLANE + row * P_STRIDE + col;
    } else {
      int k = j - 39712;
      int pd = 1 + (k / 256);
      int rj = k - (pd - 1) * 256;
      int row = 1 + (rj >> 1);
      int col = (rj & 1) ? 132 : 3;
      elem = pd * P_PLANE + row * P_STRIDE + col;
    }
    d2p[(size_t)nc * P_VOL + elem] = 0.0f;
  }
}

// ============ deconv4 cube, legacy (verified 78.6us, tier-C fallback) ============
__global__ __launch_bounds__(256) void deconv4_k(
    const float* __restrict__ d2, const float* __restrict__ w,
    const float* __restrict__ bias, float* __restrict__ out) {
  int idx = blockIdx.x * 256 + threadIdx.x;
  int c = idx & 63;
  int b = (idx >> 6) & 63;
  int a = (idx >> 12) & 7;
  int n = idx >> 15;
  float acc[2][2][2][3];
  #pragma unroll
  for (int pd = 0; pd < 2; pd++)
    #pragma unroll
    for (int ph = 0; ph < 2; ph++)
      #pragma unroll
      for (int pw = 0; pw < 2; pw++)
        #pragma unroll
        for (int co = 0; co < 3; co++) acc[pd][ph][pw][co] = bias[co];
  int ih0 = 2 * b - 1, iw0 = 2 * c - 1;
  bool vh[4], vw[4];
  #pragma unroll
  for (int l = 0; l < 4; l++) {
    vh[l] = (unsigned)(ih0 + l) < 128u;
    vw[l] = (unsigned)(iw0 + l) < 128u;
  }
  #pragma unroll 1
  for (int ci = 0; ci < 4; ci++) {
    const float* ip = d2 + ((n * 4 + ci) * 16) * 16384;
    #pragma unroll
    for (int ld = 0; ld < 4; ld++) {
      int id = 2 * a - 1 + ld;
      bool vdl = (unsigned)id < 16u;
      const float* pp = ip + id * 16384;
      float p[4][4];
      #pragma unroll
      for (int lh = 0; lh < 4; lh++)
        #pragma unroll
        for (int lw = 0; lw < 4; lw++)
          p[lh][lw] = (vdl && vh[lh] && vw[lw]) ? pp[(ih0 + lh) * 128 + (iw0 + lw)] : 0.0f;
      #pragma unroll
      for (int pd = 0; pd < 2; pd++) {
        int kd = pd + 2 - ld;
        if (kd < 0 || kd > 2) continue;
        #pragma unroll
        for (int kh = 0; kh < 3; kh++)
          #pragma unroll
          for (int kw = 0; kw < 3; kw++)
            #pragma unroll
            for (int co = 0; co < 3; co++) {
              float wv = w[(ci * 3 + co) * 27 + kd * 9 + kh * 3 + kw];
              #pragma unroll
              for (int ph = 0; ph < 2; ph++)
                #pragma unroll
                for (int pw = 0; pw < 2; pw++)
                  acc[pd][ph][pw][co] += p[ph + 2 - kh][pw + 2 - kw] * wv;
            }
      }
    }
  }
  #pragma unroll
  for (int co = 0; co < 3; co++)
    #pragma unroll
    for (int pd = 0; pd < 2; pd++)
      #pragma unroll
      for (int ph = 0; ph < 2; ph++)
        #pragma unroll
        for (int pw = 0; pw < 2; pw++)
          out[((n * 3 + co) * 16 + 2 * a + pd) * 16384 +
              (2 * b + ph) * 128 + (2 * c + pw)] = acc[pd][ph][pw][co];
}

// ============ deconv4 wide cube, padded input (R9/R11/R12 verified ~49us) ============
__global__ __launch_bounds__(256) void deconv4p_k(
    const float* __restrict__ d2p, const float* __restrict__ w,
    const float* __restrict__ bias, float* __restrict__ out) {
  int idx = blockIdx.x * 256 + threadIdx.x;
  int c = idx & 31;          // ow base 4c
  int b = (idx >> 5) & 63;   // oh base 2b
  int a = (idx >> 11) & 7;   // od base 2a
  int n = idx >> 14;
  float acc[2][2][3][4];     // [pd][ph][co][pw]
  #pragma unroll
  for (int pd = 0; pd < 2; pd++)
    #pragma unroll
    for (int ph = 0; ph < 2; ph++)
      #pragma unroll
      for (int co = 0; co < 3; co++) {
        float bv = bias[co];
        #pragma unroll
        for (int pw = 0; pw < 4; pw++) acc[pd][ph][co][pw] = bv;
      }
  #pragma unroll 1
  for (int ci = 0; ci < 4; ci++) {
    const float* ip = d2p + (size_t)(n * 4 + ci) * P_VOL +
                      (2 * a) * P_PLANE + (2 * b) * P_STRIDE + (4 * c);
    #pragma unroll
    for (int ld = 0; ld < 4; ld++) {
      const float* pp = ip + ld * P_PLANE;
      float pr[4][12];
      #pragma unroll
      for (int lh = 0; lh < 4; lh++) {
        const float* rp = pp + lh * P_STRIDE;
        float4 A = ld4(rp);
        float4 B = ld4(rp + 4);
        float4 C = ld4(rp + 8);
        pr[lh][0] = A.x;  pr[lh][1] = A.y;  pr[lh][2] = A.z;  pr[lh][3] = A.w;
        pr[lh][4] = B.x;  pr[lh][5] = B.y;  pr[lh][6] = B.z;  pr[lh][7] = B.w;
        pr[lh][8] = C.x;  pr[lh][9] = C.y;  pr[lh][10] = C.z; pr[lh][11] = C.w;
      }
      #pragma unroll
      for (int pd = 0; pd < 2; pd++) {
        int kd = pd + 2 - ld;
        if (kd < 0 || kd > 2) continue;
        #pragma unroll
        for (int kh = 0; kh < 3; kh++)
          #pragma unroll
          for (int kw = 0; kw < 3; kw++)
            #pragma unroll
            for (int co = 0; co < 3; co++) {
              float wv = w[(ci * 3 + co) * 27 + kd * 9 + kh * 3 + kw];
              #pragma unroll
              for (int ph = 0; ph < 2; ph++)
                #pragma unroll
                for (int pw = 0; pw < 4; pw++)
                  acc[pd][ph][co][pw] += pr[ph + 2 - kh][pw + 5 - kw] * wv;
            }
      }
    }
  }
  #pragma unroll
  for (int co = 0; co < 3; co++)
    #pragma unroll
    for (int pd = 0; pd < 2; pd++)
      #pragma unroll
      for (int ph = 0; ph < 2; ph++) {
        float4 o;
        o.x = acc[pd][ph][co][0]; o.y = acc[pd][ph][co][1];
        o.z = acc[pd][ph][co][2]; o.w = acc[pd][ph][co][3];
        st4(out + ((n * 3 + co) * 16 + 2 * a + pd) * 16384 +
            (2 * b + ph) * 128 + 4 * c, o);
      }
}

extern "C" void kernel_launch(void* const* d_in, const int* in_sizes, int n_in,
                              void* d_out, int out_size, void* d_ws, size_t ws_size,
                              hipStream_t stream) {
  const float* x      = (const float*)d_in[0];
  const float* enc_w1 = (const float*)d_in[2];
  const float* enc_b1 = (const float*)d_in[3];
  const float* enc_w2 = (const float*)d_in[4];
  const float* enc_b2 = (const float*)d_in[5];
  const float* enc_w4 = (const float*)d_in[6];
  const float* enc_b4 = (const float*)d_in[7];
  const float* dec_w1 = (const float*)d_in[8];
  const float* dec_b1 = (const float*)d_in[9];
  const float* dec_w3 = (const float*)d_in[10];
  const float* dec_b3 = (const float*)d_in[11];
  const float* dec_w4 = (const float*)d_in[12];
  const float* dec_b4 = (const float*)d_in[13];
  const float* emb    = (const float*)d_in[14];
  const float* csize  = (const float*)d_in[15];

  float* ws = (float*)d_ws;
  float* stats = ws;                      // 64
  float* quant = ws + 64;                 // 1,048,576
  float* z     = quant + 1048576;         // 1,048,576
  float* y2    = z + 1048576;             // 524,288
  float* y1    = y2 + 524288;             // 2,097,152 (dead after conv2)

  float* out   = (float*)d_out;                        // 12,582,912
  float* out_loss  = out + 12582912;
  float* out_codes = out_loss + 1;                     // 65,536
  float* out_perp  = out_codes + 65536;
  float* out_used  = out_perp + 1;

  // Tier A (full pad): d1p (6,082,560) + d2p (20,367,360)
  const size_t FULL_NEED = (size_t)(64 + 1048576 + 6082560 + 20367360) * sizeof(float);
  // Tier B: legacy d1 (4,194,304) + d2p
  const size_t MID_NEED  = (size_t)(64 + 1048576 + 4194304 + 20367360) * sizeof(float);

  init_stats_k<<<1, 64, 0, stream>>>(stats);

  conv1_k<<<512, 256, 0, stream>>>(x, enc_w1, enc_b1, y1);
  conv2_k<<<512, 256, 0, stream>>>(y1, enc_w2, enc_b2, y2);
  conv4_k<<<1024, 256, 0, stream>>>(y2, enc_w4, enc_b4, z);

  vq_k<<<256, 256, 0, stream>>>(z, emb, quant, out_codes, stats);
  fin_k<<<1, 64, 0, stream>>>(stats, csize, out_loss, out_perp, out_used);

  if (ws_size >= FULL_NEED) {
    float* d1p = ws + 64 + 1048576;                  // overlaps dead z/y2/y1
    float* d2p = d1p + 6082560;
    zero_halos_k<<<2048, 256, 0, stream>>>(d2p, d1p);  // after vq_k: z now dead
    deconv1_t<1><<<512, 256, 0, stream>>>(quant, dec_w1, dec_b1, d1p);
    deconv3_t<1, 1><<<2048, 256, 0, stream>>>(d1p, dec_w3, dec_b3, d2p);
    deconv4p_k<<<1024, 256, 0, stream>>>(d2p, dec_w4, dec_b4, out);
  } else if (ws_size >= MID_NEED) {
    float* d1  = ws + 64 + 1048576;
    float* d2p = d1 + 4194304;
    zero_halo_k<<<1024, 256, 0, stream>>>(d2p);
    deconv1_t<0><<<512, 256, 0, stream>>>(quant, dec_w1, dec_b1, d1);
    deconv3_t<0, 1><<<2048, 256, 0, stream>>>(d1, dec_w3, dec_b3, d2p);
    deconv4p_k<<<1024, 256, 0, stream>>>(d2p, dec_w4, dec_b4, out);
  } else {
    float* d1 = ws + 64 + 1048576;
    float* d2 = d1 + 4194304;
    deconv1_t<0><<<512, 256, 0, stream>>>(quant, dec_w1, dec_b1, d1);
    deconv3_t<0, 0><<<2048, 256, 0, stream>>>(d1, dec_w3, dec_b3, d2);
    deconv4_k<<<2048, 256, 0, stream>>>(d2, dec_w4, dec_b4, out);
  }
}